// Round 4
// baseline (6845.256 us; speedup 1.0000x reference)
//
#include <hip/hip_runtime.h>
#include <hip/hip_bf16.h>

#define N_NODES 100000
#define NFEAT 256
#define NHID 128
#define NEDGE 3200000
#define NPAIR 200000
#define NSTEPS 5

__device__ __forceinline__ float sigmoidf_(float x) {
    return 1.f / (1.f + __expf(-x));
}
__device__ __forceinline__ float bf_bits2f(unsigned short b) {
    union { float f; unsigned int u; } c; c.u = ((unsigned int)b) << 16;
    return c.f;
}

// ---------------- utility: zero f32 buffer ------------------------------------
__global__ void zero_f32(float* __restrict__ p, long long n) {
    long long i = (long long)blockIdx.x * blockDim.x + threadIdx.x;
    if (i < n) p[i] = 0.f;
}

// ---------------- row_ptr: lower_bound per node (edge_row sorted) -------------
__global__ void build_row_ptr(const int* __restrict__ rows, int E, int N, int* __restrict__ row_ptr) {
    int i = blockIdx.x * blockDim.x + threadIdx.x;
    if (i > N) return;
    int lo = 0, hi = E;
    while (lo < hi) {
        int mid = (lo + hi) >> 1;
        if (rows[mid] < i) lo = mid + 1; else hi = mid;
    }
    row_ptr[i] = lo;
}

// ---------------- pack Wcat (512 x 512) + bcat (512) --------------------------
// cols [0,128): r      rows: [Wr_in | Hr_self | Hr_nb]
// cols [128,256): i    rows: [Wi_in | Hi_self | Hi_nb]
// cols [256,384): gcn_n rows: [0    | Hh_self | Hh_nb]
// cols [384,512): in_n rows: [Wn_in | 0       | 0    ]
__global__ void pack_wcat(const float* __restrict__ Wr, const float* __restrict__ br,
                          const float* __restrict__ Wi, const float* __restrict__ bi,
                          const float* __restrict__ Wn, const float* __restrict__ bn,
                          const float* __restrict__ Hrs, const float* __restrict__ His,
                          const float* __restrict__ Hhs,
                          const float* __restrict__ Hrn, const float* __restrict__ Hin,
                          const float* __restrict__ Hhn,
                          float* __restrict__ Wcat, float* __restrict__ bcat) {
    int idx = blockIdx.x * blockDim.x + threadIdx.x;
    if (idx < 512 * 512) {
        int k = idx >> 9;
        int j = idx & 511;
        int g = j >> 7, jj = j & 127;
        float v;
        if (k < 256) {
            v = (g == 0) ? Wr[k * 128 + jj]
              : (g == 1) ? Wi[k * 128 + jj]
              : (g == 2) ? 0.f
                         : Wn[k * 128 + jj];
        } else if (k < 384) {
            int kk = k - 256;
            v = (g == 0) ? Hrs[kk * 128 + jj]
              : (g == 1) ? His[kk * 128 + jj]
              : (g == 2) ? Hhs[kk * 128 + jj]
                         : 0.f;
        } else {
            int kk = k - 384;
            v = (g == 0) ? Hrn[kk * 128 + jj]
              : (g == 1) ? Hin[kk * 128 + jj]
              : (g == 2) ? Hhn[kk * 128 + jj]
                         : 0.f;
        }
        Wcat[idx] = v;
    }
    if (idx < 512) {
        int g = idx >> 7, jj = idx & 127;
        bcat[idx] = (g == 0) ? br[jj] : (g == 1) ? bi[jj] : (g == 2) ? 0.f : bn[jj];
    }
}

// ---------------- generic f32 GEMM: C = act(A@W + bias), optional bf16 out ----
#define BM 64
#define BN 64
#define BK 32
__global__ __launch_bounds__(256) void gemm_f32(
    const float* __restrict__ A, int K,
    const float* __restrict__ W, const float* __restrict__ bias,
    void* __restrict__ C, int M, int NC, int act, int out_bf16)
{
    __shared__ float As[BK][BM + 1];
    __shared__ float Ws[BK][BN];

    const int row0 = blockIdx.x * BM;
    const int col0 = blockIdx.y * BN;
    const int tid = threadIdx.x;
    const int tm = (tid & 15) * 4;
    const int tn = (tid >> 4) * 4;

    float acc[4][4] = {};

    for (int k0 = 0; k0 < K; k0 += BK) {
        #pragma unroll
        for (int i = 0; i < 8; i++) {
            int l = tid + i * 256;
            int r = l >> 5;
            int k = l & 31;
            int gr = row0 + r;
            float v = 0.f;
            if (gr < M) v = A[(size_t)gr * K + (k0 + k)];
            As[k][r] = v;
        }
        #pragma unroll
        for (int i = 0; i < 8; i++) {
            int l = tid + i * 256;
            int k = l >> 6;
            int n = l & 63;
            Ws[k][n] = W[(size_t)(k0 + k) * NC + (col0 + n)];
        }
        __syncthreads();
        #pragma unroll
        for (int kk = 0; kk < BK; kk++) {
            float av[4];
            #pragma unroll
            for (int i = 0; i < 4; i++) av[i] = As[kk][tm + i];
            const float4 b4 = *reinterpret_cast<const float4*>(&Ws[kk][tn]);
            #pragma unroll
            for (int i = 0; i < 4; i++) {
                acc[i][0] += av[i] * b4.x;
                acc[i][1] += av[i] * b4.y;
                acc[i][2] += av[i] * b4.z;
                acc[i][3] += av[i] * b4.w;
            }
        }
        __syncthreads();
    }

    #pragma unroll
    for (int i = 0; i < 4; i++) {
        int gr = row0 + tm + i;
        if (gr >= M) continue;
        #pragma unroll
        for (int j = 0; j < 4; j++) {
            int gc = col0 + tn + j;
            float v = acc[i][j];
            if (bias) v += bias[gc];
            if (act) v = fmaxf(v, 0.f);
            size_t o = (size_t)gr * NC + gc;
            if (out_bf16) ((__hip_bfloat16*)C)[o] = __float2bfloat16(v);
            else          ((float*)C)[o] = v;
        }
    }
}

// ---------------- SpMM: hs[v,:] = sum_e w[e] * h[col[e],:]  (CSR) -------------
__global__ __launch_bounds__(256) void spmm_kernel(
    const int* __restrict__ row_ptr, const int* __restrict__ col,
    const float* __restrict__ w, const float* __restrict__ h,
    float* __restrict__ hs, int N)
{
    int v = blockIdx.x * 4 + (threadIdx.x >> 6);
    int lane = threadIdx.x & 63;
    if (v >= N) return;
    int e0 = row_ptr[v], e1 = row_ptr[v + 1];
    float a0 = 0.f, a1 = 0.f;
    for (int e = e0; e < e1; e++) {
        int c = col[e];
        float we = w[e];
        const float* hr = h + (size_t)c * NHID;
        a0 += we * hr[lane];
        a1 += we * hr[lane + 64];
    }
    hs[(size_t)v * NHID + lane] = a0;
    hs[(size_t)v * NHID + lane + 64] = a1;
}

// ---------------- fused gate GEMM + GRU update --------------------------------
// A = [inputs(256) | h(128) | hs(128)]   (K = 512)
// C panels (512 cols): [r | i | gcn_n | in_n]; gcn_n rows zero for k<256,
// in_n rows zero for k>=256 (both skipped). Epilogue: GRU, h in place.
#define DO_PANEL(p) { \
    const float4 w4 = *reinterpret_cast<const float4*>(&Ws[kk][(p) * 64 + tn]); \
    _Pragma("unroll") \
    for (int i2 = 0; i2 < 4; i2++) { \
        acc[p][i2][0] += av[i2] * w4.x; \
        acc[p][i2][1] += av[i2] * w4.y; \
        acc[p][i2][2] += av[i2] * w4.z; \
        acc[p][i2][3] += av[i2] * w4.w; } }

__global__ __launch_bounds__(256) void gate_gemm_gru(
    const float* __restrict__ inputs, const float* __restrict__ hs,
    float* __restrict__ h, const float* __restrict__ Wcat,
    const float* __restrict__ bcat, int M)
{
    __shared__ float As[16][68];
    __shared__ float Ws[16][512];

    const int row0 = blockIdx.x * 64;
    const int tid = threadIdx.x;
    const int tm = (tid & 15) * 4;   // 4 rows
    const int tn = (tid >> 4) * 4;   // 4 cols within each 64-col panel

    float acc[8][4][4] = {};

    for (int k0 = 0; k0 < 512; k0 += 16) {
        // A tile: 64 rows x 16 k, 1 float4/thread
        {
            int r = tid >> 2;
            int kq = (tid & 3) << 2;
            int gr = row0 + r, gk = k0 + kq;
            float4 v = make_float4(0.f, 0.f, 0.f, 0.f);
            if (gr < M) {
                if (gk < 256)      v = *reinterpret_cast<const float4*>(inputs + (size_t)gr * 256 + gk);
                else if (gk < 384) v = *reinterpret_cast<const float4*>(h + (size_t)gr * 128 + (gk - 256));
                else               v = *reinterpret_cast<const float4*>(hs + (size_t)gr * 128 + (gk - 384));
            }
            As[kq + 0][r] = v.x; As[kq + 1][r] = v.y; As[kq + 2][r] = v.z; As[kq + 3][r] = v.w;
        }
        // W tile: 16 k x 512 cols, 8 float4/thread
        #pragma unroll
        for (int i = 0; i < 8; i++) {
            int l = tid + i * 256;        // 0..2047
            int k = l >> 7;
            int nq = (l & 127) << 2;
            *reinterpret_cast<float4*>(&Ws[k][nq]) =
                *reinterpret_cast<const float4*>(Wcat + (size_t)(k0 + k) * 512 + nq);
        }
        __syncthreads();

        if (k0 < 256) {
            #pragma unroll
            for (int kk = 0; kk < 16; kk++) {
                const float4 a4 = *reinterpret_cast<const float4*>(&As[kk][tm]);
                const float av[4] = {a4.x, a4.y, a4.z, a4.w};
                DO_PANEL(0) DO_PANEL(1) DO_PANEL(2) DO_PANEL(3) DO_PANEL(6) DO_PANEL(7)
            }
        } else {
            #pragma unroll
            for (int kk = 0; kk < 16; kk++) {
                const float4 a4 = *reinterpret_cast<const float4*>(&As[kk][tm]);
                const float av[4] = {a4.x, a4.y, a4.z, a4.w};
                DO_PANEL(0) DO_PANEL(1) DO_PANEL(2) DO_PANEL(3) DO_PANEL(4) DO_PANEL(5)
            }
        }
        __syncthreads();
    }

    // epilogue: GRU update, thread-local gates
    #pragma unroll
    for (int i = 0; i < 4; i++) {
        int gr = row0 + tm + i;
        if (gr >= M) continue;
        size_t rb = (size_t)gr * 128;
        #pragma unroll
        for (int j = 0; j < 4; j++) {
            #pragma unroll
            for (int half = 0; half < 2; half++) {
                int c = tn + j + half * 64;      // 0..127
                float g_r = acc[0 + half][i][j] + bcat[c];
                float g_i = acc[2 + half][i][j] + bcat[128 + c];
                float g_n = acc[4 + half][i][j];               // gcn part of n
                float g_in = acc[6 + half][i][j] + bcat[384 + c]; // in_n + bn
                float r = sigmoidf_(g_r);
                float ii = sigmoidf_(g_i);
                float n = tanhf(g_in + r * g_n);
                float hold = h[rb + c];
                h[rb + c] = (1.f - ii) * n + ii * hold;
            }
        }
    }
}

// ---------------- LayerNorm (torch variant) -> f32 z out ----------------------
__global__ __launch_bounds__(256) void layernorm_kernel(
    const float* __restrict__ x, const float* __restrict__ gamma,
    const float* __restrict__ beta, float* __restrict__ zout, int N)
{
    int v = blockIdx.x * 4 + (threadIdx.x >> 6);
    int lane = threadIdx.x & 63;
    if (v >= N) return;
    const float* xr = x + (size_t)v * NHID;
    float x0 = xr[lane], x1 = xr[lane + 64];
    float s = x0 + x1;
    #pragma unroll
    for (int off = 32; off; off >>= 1) s += __shfl_xor(s, off, 64);
    float mean = s * (1.f / 128.f);
    float d0 = x0 - mean, d1 = x1 - mean;
    float vs = d0 * d0 + d1 * d1;
    #pragma unroll
    for (int off = 32; off; off >>= 1) vs += __shfl_xor(vs, off, 64);
    float std_ = sqrtf(vs / 127.f);
    float inv = 1.f / (std_ + 1e-6f);
    size_t o = (size_t)v * NHID;
    zout[o + lane] = gamma[lane] * d0 * inv + beta[lane];
    zout[o + lane + 64] = gamma[lane + 64] * d1 * inv + beta[lane + 64];
}

// ---------------- pair decoder: d = sigmoid(sum_j relu(U[x]+V[y]+b1)*w2 + b2) -
__global__ __launch_bounds__(256) void decoder_pairs(
    const unsigned short* __restrict__ U, const unsigned short* __restrict__ V,
    const int* __restrict__ xi, const int* __restrict__ yi,
    const float* __restrict__ bd1, const float* __restrict__ Wd2,
    const float* __restrict__ bd2, float* __restrict__ dout, int P)
{
    __shared__ float b1s[128], w2s[128];
    if (threadIdx.x < 128) {
        b1s[threadIdx.x] = bd1[threadIdx.x];
        w2s[threadIdx.x] = Wd2[threadIdx.x];
    }
    __syncthreads();
    int p = blockIdx.x * 256 + threadIdx.x;
    if (p >= P) return;
    const unsigned short* ur = U + (size_t)xi[p] * 128;
    const unsigned short* vr = V + (size_t)yi[p] * 128;
    float part = 0.f;
    #pragma unroll
    for (int j0 = 0; j0 < 128; j0 += 8) {
        const uint4 ua = *reinterpret_cast<const uint4*>(ur + j0);
        const uint4 va = *reinterpret_cast<const uint4*>(vr + j0);
        float uf[8], vf[8];
        uf[0] = bf_bits2f((unsigned short)ua.x); uf[1] = bf_bits2f((unsigned short)(ua.x >> 16));
        uf[2] = bf_bits2f((unsigned short)ua.y); uf[3] = bf_bits2f((unsigned short)(ua.y >> 16));
        uf[4] = bf_bits2f((unsigned short)ua.z); uf[5] = bf_bits2f((unsigned short)(ua.z >> 16));
        uf[6] = bf_bits2f((unsigned short)ua.w); uf[7] = bf_bits2f((unsigned short)(ua.w >> 16));
        vf[0] = bf_bits2f((unsigned short)va.x); vf[1] = bf_bits2f((unsigned short)(va.x >> 16));
        vf[2] = bf_bits2f((unsigned short)va.y); vf[3] = bf_bits2f((unsigned short)(va.y >> 16));
        vf[4] = bf_bits2f((unsigned short)va.z); vf[5] = bf_bits2f((unsigned short)(va.z >> 16));
        vf[6] = bf_bits2f((unsigned short)va.w); vf[7] = bf_bits2f((unsigned short)(va.w >> 16));
        #pragma unroll
        for (int q = 0; q < 8; q++) {
            float t = uf[q] + vf[q] + b1s[j0 + q];
            part += fmaxf(t, 0.f) * w2s[j0 + q];
        }
    }
    dout[p] = sigmoidf_(part + bd2[0]);
}

// ---------------- launcher ----------------------------------------------------
extern "C" void kernel_launch(void* const* d_in, const int* in_sizes, int n_in,
                              void* d_out, int out_size, void* d_ws, size_t ws_size,
                              hipStream_t stream) {
    const float* inputs = (const float*)d_in[0];
    const int* edge_row = (const int*)d_in[1];
    const int* edge_col = (const int*)d_in[2];
    const float* edge_w = (const float*)d_in[3];
    const int* x_idx = (const int*)d_in[4];
    const int* y_idx = (const int*)d_in[5];
    const float* Wr_in = (const float*)d_in[6];  const float* br_in = (const float*)d_in[7];
    const float* Wi_in = (const float*)d_in[8];  const float* bi_in = (const float*)d_in[9];
    const float* Wn_in = (const float*)d_in[10]; const float* bn_in = (const float*)d_in[11];
    const float* Hr_self = (const float*)d_in[12]; const float* Hr_nb = (const float*)d_in[13];
    const float* Hi_self = (const float*)d_in[14]; const float* Hi_nb = (const float*)d_in[15];
    const float* Hh_self = (const float*)d_in[16]; const float* Hh_nb = (const float*)d_in[17];
    const float* W1 = (const float*)d_in[18]; const float* b1 = (const float*)d_in[19];
    const float* W2 = (const float*)d_in[20]; const float* b2 = (const float*)d_in[21];
    const float* W3 = (const float*)d_in[22]; const float* b3 = (const float*)d_in[23];
    const float* gamma = (const float*)d_in[24]; const float* beta = (const float*)d_in[25];
    const float* Wd1 = (const float*)d_in[26]; const float* bd1 = (const float*)d_in[27];
    const float* Wd2 = (const float*)d_in[28]; const float* bd2 = (const float*)d_in[29];

    // OUTPUT IS FLOAT32 (reference returns f32; harness reads f32)
    float* out_d = (float*)d_out;            // [P]
    float* out_z = ((float*)d_out) + NPAIR;  // [N*128]

    // ---- workspace layout (~104 MB) ----
    char* base = (char*)d_ws;
    size_t off = 0;
    auto take = [&](size_t bytes) { void* p = base + off; off = (off + bytes + 255) & ~(size_t)255; return p; };
    int*   row_ptr = (int*)  take((size_t)(N_NODES + 1) * 4);
    float* Wcat    = (float*)take((size_t)512 * 512 * 4);
    float* bcat    = (float*)take(512 * 4);
    float* bufA    = (float*)take((size_t)N_NODES * NHID * 4);   // h / x2 / U,V(bf16)
    float* bufB    = (float*)take((size_t)N_NODES * NHID * 4);   // hs / x1 / x3
    if (off > ws_size) return;   // diagnostic marker: d stays 0 -> absmax == 0.586

    float* h  = bufA;
    float* hs = bufB;

    // 1. CSR row_ptr
    build_row_ptr<<<(N_NODES + 256) / 256, 256, 0, stream>>>(edge_row, NEDGE, N_NODES, row_ptr);
    // 2. pack combined weights (512x512)
    pack_wcat<<<(512 * 512 + 255) / 256, 256, 0, stream>>>(
        Wr_in, br_in, Wi_in, bi_in, Wn_in, bn_in,
        Hr_self, Hi_self, Hh_self, Hr_nb, Hi_nb, Hh_nb, Wcat, bcat);
    // 3. h = 0
    {
        long long n = (long long)N_NODES * NHID;
        zero_f32<<<(unsigned)((n + 255) / 256), 256, 0, stream>>>(h, n);
    }
    // 4. recurrent steps: spmm -> fused gate GEMM + GRU (h updated in place)
    for (int s = 0; s < NSTEPS; s++) {
        spmm_kernel<<<(N_NODES + 3) / 4, 256, 0, stream>>>(row_ptr, edge_col, edge_w, h, hs, N_NODES);
        gate_gemm_gru<<<(N_NODES + 63) / 64, 256, 0, stream>>>(inputs, hs, h, Wcat, bcat, N_NODES);
    }
    // 5. MLP: h(bufA) -> x1(bufB) -> x2(bufA) -> x3(bufB)
    {
        dim3 grid((N_NODES + BM - 1) / BM, NHID / BN);
        gemm_f32<<<grid, 256, 0, stream>>>(h,    NHID, W1, b1, bufB, N_NODES, NHID, 1, 0);
        gemm_f32<<<grid, 256, 0, stream>>>(bufB, NHID, W2, b2, bufA, N_NODES, NHID, 1, 0);
        gemm_f32<<<grid, 256, 0, stream>>>(bufA, NHID, W3, b3, bufB, N_NODES, NHID, 1, 0);
    }
    // 6. LayerNorm: x3(bufB) -> f32 z directly in d_out
    layernorm_kernel<<<(N_NODES + 3) / 4, 256, 0, stream>>>(bufB, gamma, beta, out_z, N_NODES);
    // 7. U = z @ Wd1[0:128], V = z @ Wd1[128:256]  (bf16 into bufA)
    {
        unsigned short* Ub = (unsigned short*)bufA;
        unsigned short* Vb = Ub + (size_t)N_NODES * NHID;
        dim3 grid((N_NODES + BM - 1) / BM, NHID / BN);
        gemm_f32<<<grid, 256, 0, stream>>>(out_z, NHID, Wd1,             nullptr, Ub, N_NODES, NHID, 0, 1);
        gemm_f32<<<grid, 256, 0, stream>>>(out_z, NHID, Wd1 + 128 * 128, nullptr, Vb, N_NODES, NHID, 0, 1);
        // 8. pair decoder -> d (f32)
        decoder_pairs<<<(NPAIR + 255) / 256, 256, 0, stream>>>(
            Ub, Vb, x_idx, y_idx, bd1, Wd2, bd2, out_d, NPAIR);
    }
}

// Round 5
// 3099.275 us; speedup vs baseline: 2.2087x; 2.2087x over previous
//
#include <hip/hip_runtime.h>
#include <hip/hip_bf16.h>

#define N_NODES 100000
#define NFEAT 256
#define NHID 128
#define NEDGE 3200000
#define NPAIR 200000
#define NSTEPS 5

typedef __attribute__((ext_vector_type(8))) short short8x;   // 8 bf16 (4 VGPR)
typedef __attribute__((ext_vector_type(4))) float f32x4;

__device__ __forceinline__ float sigmoidf_(float x) {
    return 1.f / (1.f + __expf(-x));
}
__device__ __forceinline__ unsigned short f2bf_bits(float f) {
    union { float f; unsigned int u; } c; c.f = f;
    unsigned int r = (c.u + 0x7FFFu + ((c.u >> 16) & 1u)) >> 16;
    return (unsigned short)r;
}
__device__ __forceinline__ float bf_bits2f(unsigned short b) {
    union { float f; unsigned int u; } c; c.u = ((unsigned int)b) << 16;
    return c.f;
}

// ---------------- utility: zero h (f32) + h_bf (bf16) -------------------------
__global__ void zero_state(float* __restrict__ h, unsigned short* __restrict__ hbf, long long n) {
    long long i = (long long)blockIdx.x * blockDim.x + threadIdx.x;
    if (i < n) { h[i] = 0.f; hbf[i] = 0; }
}

// ---------------- row_ptr: lower_bound per node (edge_row sorted) -------------
__global__ void build_row_ptr(const int* __restrict__ rows, int E, int N, int* __restrict__ row_ptr) {
    int i = blockIdx.x * blockDim.x + threadIdx.x;
    if (i > N) return;
    int lo = 0, hi = E;
    while (lo < hi) {
        int mid = (lo + hi) >> 1;
        if (rows[mid] < i) lo = mid + 1; else hi = mid;
    }
    row_ptr[i] = lo;
}

// ---------------- pack WB: bf16, K-step-major [16][512 cols][32 k] ------------
// col panels: [0,128): r  [128,256): i  [256,384): gcn_n  [384,512): in_n
// k rows: [0,256): input weights (gcn_n zero)  [256,384): H*_self (in_n zero)
//         [384,512): H*_nb (in_n zero)
__global__ void pack_wb(const float* __restrict__ Wr, const float* __restrict__ br,
                        const float* __restrict__ Wi, const float* __restrict__ bi,
                        const float* __restrict__ Wn, const float* __restrict__ bn,
                        const float* __restrict__ Hrs, const float* __restrict__ His,
                        const float* __restrict__ Hhs,
                        const float* __restrict__ Hrn, const float* __restrict__ Hin,
                        const float* __restrict__ Hhn,
                        unsigned short* __restrict__ WB, float* __restrict__ bcat) {
    int idx = blockIdx.x * blockDim.x + threadIdx.x;
    if (idx < 512 * 512) {
        int kg = idx >> 9;          // global k 0..511
        int c  = idx & 511;         // col 0..511
        int g = c >> 7, jj = c & 127;
        float v;
        if (kg < 256) {
            v = (g == 0) ? Wr[kg * 128 + jj]
              : (g == 1) ? Wi[kg * 128 + jj]
              : (g == 2) ? 0.f
                         : Wn[kg * 128 + jj];
        } else if (kg < 384) {
            int kk = kg - 256;
            v = (g == 0) ? Hrs[kk * 128 + jj]
              : (g == 1) ? His[kk * 128 + jj]
              : (g == 2) ? Hhs[kk * 128 + jj]
                         : 0.f;
        } else {
            int kk = kg - 384;
            v = (g == 0) ? Hrn[kk * 128 + jj]
              : (g == 1) ? Hin[kk * 128 + jj]
              : (g == 2) ? Hhn[kk * 128 + jj]
                         : 0.f;
        }
        int s = kg >> 5, k = kg & 31;
        WB[(size_t)s * 16384 + c * 32 + k] = f2bf_bits(v);
    }
    if (idx < 512) {
        int g = idx >> 7, jj = idx & 127;
        bcat[idx] = (g == 0) ? br[jj] : (g == 1) ? bi[jj] : (g == 2) ? 0.f : bn[jj];
    }
}

// ---------------- generic f32 GEMM: C = act(A@W + bias), optional bf16 out ----
#define BM 64
#define BN 64
#define BK 32
__global__ __launch_bounds__(256) void gemm_f32(
    const float* __restrict__ A, int K,
    const float* __restrict__ W, const float* __restrict__ bias,
    void* __restrict__ C, int M, int NC, int act, int out_bf16)
{
    __shared__ float As[BK][BM + 1];
    __shared__ float Ws[BK][BN];

    const int row0 = blockIdx.x * BM;
    const int col0 = blockIdx.y * BN;
    const int tid = threadIdx.x;
    const int tm = (tid & 15) * 4;
    const int tn = (tid >> 4) * 4;

    float acc[4][4] = {};

    for (int k0 = 0; k0 < K; k0 += BK) {
        #pragma unroll
        for (int i = 0; i < 8; i++) {
            int l = tid + i * 256;
            int r = l >> 5;
            int k = l & 31;
            int gr = row0 + r;
            float v = 0.f;
            if (gr < M) v = A[(size_t)gr * K + (k0 + k)];
            As[k][r] = v;
        }
        #pragma unroll
        for (int i = 0; i < 8; i++) {
            int l = tid + i * 256;
            int k = l >> 6;
            int n = l & 63;
            Ws[k][n] = W[(size_t)(k0 + k) * NC + (col0 + n)];
        }
        __syncthreads();
        #pragma unroll
        for (int kk = 0; kk < BK; kk++) {
            float av[4];
            #pragma unroll
            for (int i = 0; i < 4; i++) av[i] = As[kk][tm + i];
            const float4 b4 = *reinterpret_cast<const float4*>(&Ws[kk][tn]);
            #pragma unroll
            for (int i = 0; i < 4; i++) {
                acc[i][0] += av[i] * b4.x;
                acc[i][1] += av[i] * b4.y;
                acc[i][2] += av[i] * b4.z;
                acc[i][3] += av[i] * b4.w;
            }
        }
        __syncthreads();
    }

    #pragma unroll
    for (int i = 0; i < 4; i++) {
        int gr = row0 + tm + i;
        if (gr >= M) continue;
        #pragma unroll
        for (int j = 0; j < 4; j++) {
            int gc = col0 + tn + j;
            float v = acc[i][j];
            if (bias) v += bias[gc];
            if (act) v = fmaxf(v, 0.f);
            size_t o = (size_t)gr * NC + gc;
            if (out_bf16) ((unsigned short*)C)[o] = f2bf_bits(v);
            else          ((float*)C)[o] = v;
        }
    }
}

// ---------------- SpMM (bf16): hs_bf[v,:] = sum_e w[e] * h_bf[col[e],:] -------
__global__ __launch_bounds__(256) void spmm_bf16(
    const int* __restrict__ row_ptr, const int* __restrict__ col,
    const float* __restrict__ w, const unsigned short* __restrict__ hbf,
    unsigned short* __restrict__ hsbf, int N)
{
    int v = blockIdx.x * 4 + (threadIdx.x >> 6);
    int lane = threadIdx.x & 63;
    if (v >= N) return;
    int c0 = lane * 2;
    int e0 = row_ptr[v], e1 = row_ptr[v + 1];
    float a0 = 0.f, a1 = 0.f;
    for (int e = e0; e < e1; e++) {
        int cc = col[e];
        float we = w[e];
        unsigned int hv = *reinterpret_cast<const unsigned int*>(hbf + (size_t)cc * NHID + c0);
        a0 += we * bf_bits2f((unsigned short)hv);
        a1 += we * bf_bits2f((unsigned short)(hv >> 16));
    }
    unsigned int out = (unsigned int)f2bf_bits(a0) | ((unsigned int)f2bf_bits(a1) << 16);
    *reinterpret_cast<unsigned int*>(hsbf + (size_t)v * NHID + c0) = out;
}

// ---------------- fused bf16-MFMA gate GEMM + GRU update ----------------------
// A = [inputs(256, f32->bf16 in-flight) | h_bf(128) | hs_bf(128)], K=512
// Output 512 cols = 4 panels [r|i|gcn_n|in_n]; wave w owns cols == [32w,32w+32)
// mod 128 across all 4 panels -> GRU epilogue fully thread-local.
__global__ __launch_bounds__(256) void gate_mfma_gru(
    const float* __restrict__ inputs, const unsigned short* __restrict__ hsbf,
    float* __restrict__ h, unsigned short* __restrict__ hbf,
    const unsigned short* __restrict__ WB, const float* __restrict__ bcat, int M)
{
    __shared__ unsigned short As[64 * 40];    // 64 rows x 32 k, stride 40 (pad)
    __shared__ unsigned short Bs[512 * 40];   // 512 cols x 32 k, stride 40
    __shared__ float bcs[512];

    const int tid = threadIdx.x;
    const int wid = tid >> 6;
    const int lane = tid & 63;
    const int row0 = blockIdx.x * 64;
    const int l15 = lane & 15;
    const int lhi = lane >> 4;      // 0..3

    for (int i = tid; i < 512; i += 256) bcs[i] = bcat[i];

    f32x4 acc[4][2][4] = {};        // [panel][colblk][rowblk]

    const int ar = tid >> 2;        // A-stage row 0..63
    const int aq = tid & 3;         // A-stage k-chunk
    const int agr = row0 + ar;

    for (int s = 0; s < 16; s++) {
        // ---- stage A (64x32 bf16): source uniform per s ----
        {
            short8x va = short8x(0);
            if (agr < M) {
                if (s < 8) {
                    // f32 inputs -> bf16 in flight
                    const float* src = inputs + (size_t)agr * 256 + s * 32 + aq * 8;
                    const float4 f0 = *reinterpret_cast<const float4*>(src);
                    const float4 f1 = *reinterpret_cast<const float4*>(src + 4);
                    va[0] = (short)f2bf_bits(f0.x); va[1] = (short)f2bf_bits(f0.y);
                    va[2] = (short)f2bf_bits(f0.z); va[3] = (short)f2bf_bits(f0.w);
                    va[4] = (short)f2bf_bits(f1.x); va[5] = (short)f2bf_bits(f1.y);
                    va[6] = (short)f2bf_bits(f1.z); va[7] = (short)f2bf_bits(f1.w);
                } else if (s < 12) {
                    va = *reinterpret_cast<const short8x*>(hbf + (size_t)agr * 128 + (s - 8) * 32 + aq * 8);
                } else {
                    va = *reinterpret_cast<const short8x*>(hsbf + (size_t)agr * 128 + (s - 12) * 32 + aq * 8);
                }
            }
            *reinterpret_cast<short8x*>(&As[ar * 40 + aq * 8]) = va;
        }
        // ---- stage B (512x32 bf16, linear from WB) ----
        {
            const unsigned short* wbs = WB + (size_t)s * 16384;
            #pragma unroll
            for (int i = 0; i < 8; i++) {
                int id = tid + i * 256;           // 0..2047
                int c = id >> 2, q = id & 3;
                short8x vb = *reinterpret_cast<const short8x*>(wbs + id * 8);
                *reinterpret_cast<short8x*>(&Bs[c * 40 + q * 8]) = vb;
            }
        }
        __syncthreads();

        // ---- MFMA ----
        short8x a[4];
        #pragma unroll
        for (int rb = 0; rb < 4; rb++)
            a[rb] = *reinterpret_cast<const short8x*>(&As[(16 * rb + l15) * 40 + lhi * 8]);
        #pragma unroll
        for (int p = 0; p < 4; p++) {
            #pragma unroll
            for (int cb = 0; cb < 2; cb++) {
                int c0 = 128 * p + 32 * wid + 16 * cb + l15;
                short8x b = *reinterpret_cast<const short8x*>(&Bs[c0 * 40 + lhi * 8]);
                #pragma unroll
                for (int rb = 0; rb < 4; rb++)
                    acc[p][cb][rb] = __builtin_amdgcn_mfma_f32_16x16x32_bf16(a[rb], b, acc[p][cb][rb], 0, 0, 0);
            }
        }
        __syncthreads();
    }

    // ---- GRU epilogue: thread-local gates ----
    #pragma unroll
    for (int rb = 0; rb < 4; rb++) {
        #pragma unroll
        for (int cb = 0; cb < 2; cb++) {
            int c = 32 * wid + 16 * cb + l15;     // hidden unit 0..127
            #pragma unroll
            for (int j = 0; j < 4; j++) {
                int row = row0 + 16 * rb + lhi * 4 + j;
                if (row < M) {
                    float g_r  = acc[0][cb][rb][j] + bcs[c];
                    float g_i  = acc[1][cb][rb][j] + bcs[128 + c];
                    float g_n  = acc[2][cb][rb][j];
                    float g_in = acc[3][cb][rb][j] + bcs[384 + c];
                    float rr = sigmoidf_(g_r);
                    float ii = sigmoidf_(g_i);
                    float nn = tanhf(g_in + rr * g_n);
                    size_t o = (size_t)row * 128 + c;
                    float hnew = (1.f - ii) * nn + ii * h[o];
                    h[o] = hnew;
                    hbf[o] = f2bf_bits(hnew);
                }
            }
        }
    }
}

// ---------------- LayerNorm (torch variant) -> f32 z out ----------------------
__global__ __launch_bounds__(256) void layernorm_kernel(
    const float* __restrict__ x, const float* __restrict__ gamma,
    const float* __restrict__ beta, float* __restrict__ zout, int N)
{
    int v = blockIdx.x * 4 + (threadIdx.x >> 6);
    int lane = threadIdx.x & 63;
    if (v >= N) return;
    const float* xr = x + (size_t)v * NHID;
    float x0 = xr[lane], x1 = xr[lane + 64];
    float s = x0 + x1;
    #pragma unroll
    for (int off = 32; off; off >>= 1) s += __shfl_xor(s, off, 64);
    float mean = s * (1.f / 128.f);
    float d0 = x0 - mean, d1 = x1 - mean;
    float vs = d0 * d0 + d1 * d1;
    #pragma unroll
    for (int off = 32; off; off >>= 1) vs += __shfl_xor(vs, off, 64);
    float std_ = sqrtf(vs / 127.f);
    float inv = 1.f / (std_ + 1e-6f);
    size_t o = (size_t)v * NHID;
    zout[o + lane] = gamma[lane] * d0 * inv + beta[lane];
    zout[o + lane + 64] = gamma[lane + 64] * d1 * inv + beta[lane + 64];
}

// ---------------- pair decoder: d = sigmoid(sum_j relu(U[x]+V[y]+b1)*w2 + b2) -
__global__ __launch_bounds__(256) void decoder_pairs(
    const unsigned short* __restrict__ U, const unsigned short* __restrict__ V,
    const int* __restrict__ xi, const int* __restrict__ yi,
    const float* __restrict__ bd1, const float* __restrict__ Wd2,
    const float* __restrict__ bd2, float* __restrict__ dout, int P)
{
    __shared__ float b1s[128], w2s[128];
    if (threadIdx.x < 128) {
        b1s[threadIdx.x] = bd1[threadIdx.x];
        w2s[threadIdx.x] = Wd2[threadIdx.x];
    }
    __syncthreads();
    int p = blockIdx.x * 256 + threadIdx.x;
    if (p >= P) return;
    const unsigned short* ur = U + (size_t)xi[p] * 128;
    const unsigned short* vr = V + (size_t)yi[p] * 128;
    float part = 0.f;
    #pragma unroll
    for (int j0 = 0; j0 < 128; j0 += 8) {
        const uint4 ua = *reinterpret_cast<const uint4*>(ur + j0);
        const uint4 va = *reinterpret_cast<const uint4*>(vr + j0);
        float uf[8], vf[8];
        uf[0] = bf_bits2f((unsigned short)ua.x); uf[1] = bf_bits2f((unsigned short)(ua.x >> 16));
        uf[2] = bf_bits2f((unsigned short)ua.y); uf[3] = bf_bits2f((unsigned short)(ua.y >> 16));
        uf[4] = bf_bits2f((unsigned short)ua.z); uf[5] = bf_bits2f((unsigned short)(ua.z >> 16));
        uf[6] = bf_bits2f((unsigned short)ua.w); uf[7] = bf_bits2f((unsigned short)(ua.w >> 16));
        vf[0] = bf_bits2f((unsigned short)va.x); vf[1] = bf_bits2f((unsigned short)(va.x >> 16));
        vf[2] = bf_bits2f((unsigned short)va.y); vf[3] = bf_bits2f((unsigned short)(va.y >> 16));
        vf[4] = bf_bits2f((unsigned short)va.z); vf[5] = bf_bits2f((unsigned short)(va.z >> 16));
        vf[6] = bf_bits2f((unsigned short)va.w); vf[7] = bf_bits2f((unsigned short)(va.w >> 16));
        #pragma unroll
        for (int q = 0; q < 8; q++) {
            float t = uf[q] + vf[q] + b1s[j0 + q];
            part += fmaxf(t, 0.f) * w2s[j0 + q];
        }
    }
    dout[p] = sigmoidf_(part + bd2[0]);
}

// ---------------- launcher ----------------------------------------------------
extern "C" void kernel_launch(void* const* d_in, const int* in_sizes, int n_in,
                              void* d_out, int out_size, void* d_ws, size_t ws_size,
                              hipStream_t stream) {
    const float* inputs = (const float*)d_in[0];
    const int* edge_row = (const int*)d_in[1];
    const int* edge_col = (const int*)d_in[2];
    const float* edge_w = (const float*)d_in[3];
    const int* x_idx = (const int*)d_in[4];
    const int* y_idx = (const int*)d_in[5];
    const float* Wr_in = (const float*)d_in[6];  const float* br_in = (const float*)d_in[7];
    const float* Wi_in = (const float*)d_in[8];  const float* bi_in = (const float*)d_in[9];
    const float* Wn_in = (const float*)d_in[10]; const float* bn_in = (const float*)d_in[11];
    const float* Hr_self = (const float*)d_in[12]; const float* Hr_nb = (const float*)d_in[13];
    const float* Hi_self = (const float*)d_in[14]; const float* Hi_nb = (const float*)d_in[15];
    const float* Hh_self = (const float*)d_in[16]; const float* Hh_nb = (const float*)d_in[17];
    const float* W1 = (const float*)d_in[18]; const float* b1 = (const float*)d_in[19];
    const float* W2 = (const float*)d_in[20]; const float* b2 = (const float*)d_in[21];
    const float* W3 = (const float*)d_in[22]; const float* b3 = (const float*)d_in[23];
    const float* gamma = (const float*)d_in[24]; const float* beta = (const float*)d_in[25];
    const float* Wd1 = (const float*)d_in[26]; const float* bd1 = (const float*)d_in[27];
    const float* Wd2 = (const float*)d_in[28]; const float* bd2 = (const float*)d_in[29];

    float* out_d = (float*)d_out;            // [P]
    float* out_z = ((float*)d_out) + NPAIR;  // [N*128]

    // ---- workspace layout (~104 MB, proven fit) ----
    char* base = (char*)d_ws;
    size_t off = 0;
    auto take = [&](size_t bytes) { void* p = base + off; off = (off + bytes + 255) & ~(size_t)255; return p; };
    int*            row_ptr = (int*)           take((size_t)(N_NODES + 1) * 4);
    unsigned short* WB      = (unsigned short*)take((size_t)512 * 512 * 2);
    float*          bcat    = (float*)         take(512 * 4);
    float*          h       = (float*)         take((size_t)N_NODES * NHID * 4);   // later x2 / U,V(bf16)
    unsigned short* hbf     = (unsigned short*)take((size_t)N_NODES * NHID * 2);   // \ contiguous: later
    unsigned short* hsbf    = (unsigned short*)take((size_t)N_NODES * NHID * 2);   // / bufC f32 (x1/x3)
    if (off > ws_size) return;   // diagnostic marker: d stays 0 -> absmax == 0.586

    float* bufC = (float*)hbf;   // 51.2 MB f32 view of hbf+hsbf (post-recurrence)

    // 1. CSR row_ptr
    build_row_ptr<<<(N_NODES + 256) / 256, 256, 0, stream>>>(edge_row, NEDGE, N_NODES, row_ptr);
    // 2. pack bf16 K-major weights + bias
    pack_wb<<<(512 * 512 + 255) / 256, 256, 0, stream>>>(
        Wr_in, br_in, Wi_in, bi_in, Wn_in, bn_in,
        Hr_self, Hi_self, Hh_self, Hr_nb, Hi_nb, Hh_nb, WB, bcat);
    // 3. h = 0 (f32 + bf16 mirror)
    {
        long long n = (long long)N_NODES * NHID;
        zero_state<<<(unsigned)((n + 255) / 256), 256, 0, stream>>>(h, hbf, n);
    }
    // 4. recurrent steps
    for (int s = 0; s < NSTEPS; s++) {
        spmm_bf16<<<(N_NODES + 3) / 4, 256, 0, stream>>>(row_ptr, edge_col, edge_w, hbf, hsbf, N_NODES);
        gate_mfma_gru<<<(N_NODES + 63) / 64, 256, 0, stream>>>(inputs, hsbf, h, hbf, WB, bcat, N_NODES);
    }
    // 5. MLP: h -> x1(bufC) -> x2(h region) -> x3(bufC)
    {
        float* x2 = h;
        dim3 grid((N_NODES + BM - 1) / BM, NHID / BN);
        gemm_f32<<<grid, 256, 0, stream>>>(h,    NHID, W1, b1, bufC, N_NODES, NHID, 1, 0);
        gemm_f32<<<grid, 256, 0, stream>>>(bufC, NHID, W2, b2, x2,   N_NODES, NHID, 1, 0);
        gemm_f32<<<grid, 256, 0, stream>>>(x2,   NHID, W3, b3, bufC, N_NODES, NHID, 1, 0);
    }
    // 6. LayerNorm: x3(bufC) -> f32 z directly in d_out
    layernorm_kernel<<<(N_NODES + 3) / 4, 256, 0, stream>>>(bufC, gamma, beta, out_z, N_NODES);
    // 7. U = z @ Wd1[0:128], V = z @ Wd1[128:256]  (bf16 into h region)
    {
        unsigned short* Ub = (unsigned short*)h;
        unsigned short* Vb = Ub + (size_t)N_NODES * NHID;
        dim3 grid((N_NODES + BM - 1) / BM, NHID / BN);
        gemm_f32<<<grid, 256, 0, stream>>>(out_z, NHID, Wd1,             nullptr, Ub, N_NODES, NHID, 0, 1);
        gemm_f32<<<grid, 256, 0, stream>>>(out_z, NHID, Wd1 + 128 * 128, nullptr, Vb, N_NODES, NHID, 0, 1);
        // 8. pair decoder -> d (f32)
        decoder_pairs<<<(NPAIR + 255) / 256, 256, 0, stream>>>(
            Ub, Vb, x_idx, y_idx, bd1, Wd2, bd2, out_d, NPAIR);
    }
}

// Round 6
// 1874.050 us; speedup vs baseline: 3.6527x; 1.6538x over previous
//
#include <hip/hip_runtime.h>
#include <hip/hip_bf16.h>

#define N_NODES 100000
#define NFEAT 256
#define NHID 128
#define NEDGE 3200000
#define NPAIR 200000
#define NSTEPS 5

typedef __attribute__((ext_vector_type(8))) short short8x;   // 8 bf16 (4 VGPR)
typedef __attribute__((ext_vector_type(4))) float f32x4;

__device__ __forceinline__ float sigmoidf_(float x) {
    return 1.f / (1.f + __expf(-x));
}
__device__ __forceinline__ unsigned short f2bf_bits(float f) {
    union { float f; unsigned int u; } c; c.f = f;
    unsigned int r = (c.u + 0x7FFFu + ((c.u >> 16) & 1u)) >> 16;
    return (unsigned short)r;
}
__device__ __forceinline__ float bf_bits2f(unsigned short b) {
    union { float f; unsigned int u; } c; c.u = ((unsigned int)b) << 16;
    return c.f;
}

// ---------------- utility: zero h (f32) + h_bf (bf16) -------------------------
__global__ void zero_state(float* __restrict__ h, unsigned short* __restrict__ hbf, long long n) {
    long long i = (long long)blockIdx.x * blockDim.x + threadIdx.x;
    if (i < n) { h[i] = 0.f; hbf[i] = 0; }
}

// ---------------- row_ptr: lower_bound per node (edge_row sorted) -------------
__global__ void build_row_ptr(const int* __restrict__ rows, int E, int N, int* __restrict__ row_ptr) {
    int i = blockIdx.x * blockDim.x + threadIdx.x;
    if (i > N) return;
    int lo = 0, hi = E;
    while (lo < hi) {
        int mid = (lo + hi) >> 1;
        if (rows[mid] < i) lo = mid + 1; else hi = mid;
    }
    row_ptr[i] = lo;
}

// ---------------- pack WB: bf16, K-step-major [16][512 cols][32 k] ------------
__global__ void pack_wb(const float* __restrict__ Wr, const float* __restrict__ br,
                        const float* __restrict__ Wi, const float* __restrict__ bi,
                        const float* __restrict__ Wn, const float* __restrict__ bn,
                        const float* __restrict__ Hrs, const float* __restrict__ His,
                        const float* __restrict__ Hhs,
                        const float* __restrict__ Hrn, const float* __restrict__ Hin,
                        const float* __restrict__ Hhn,
                        unsigned short* __restrict__ WB, float* __restrict__ bcat) {
    int idx = blockIdx.x * blockDim.x + threadIdx.x;
    if (idx < 512 * 512) {
        int kg = idx >> 9;          // global k 0..511
        int c  = idx & 511;         // col 0..511
        int g = c >> 7, jj = c & 127;
        float v;
        if (kg < 256) {
            v = (g == 0) ? Wr[kg * 128 + jj]
              : (g == 1) ? Wi[kg * 128 + jj]
              : (g == 2) ? 0.f
                         : Wn[kg * 128 + jj];
        } else if (kg < 384) {
            int kk = kg - 256;
            v = (g == 0) ? Hrs[kk * 128 + jj]
              : (g == 1) ? His[kk * 128 + jj]
              : (g == 2) ? Hhs[kk * 128 + jj]
                         : 0.f;
        } else {
            int kk = kg - 384;
            v = (g == 0) ? Hrn[kk * 128 + jj]
              : (g == 1) ? Hin[kk * 128 + jj]
              : (g == 2) ? Hhn[kk * 128 + jj]
                         : 0.f;
        }
        int s = kg >> 5, k = kg & 31;
        WB[(size_t)s * 16384 + c * 32 + k] = f2bf_bits(v);
    }
    if (idx < 512) {
        int g = idx >> 7, jj = idx & 127;
        bcat[idx] = (g == 0) ? br[jj] : (g == 1) ? bi[jj] : (g == 2) ? 0.f : bn[jj];
    }
}

// ---------------- pack a K x NCsrc f32 weight to K-step-major bf16 ------------
// out[s][coff + j][k&31], total col stride NCtot
__global__ void pack_kmajor(const float* __restrict__ W, int K, int NCsrc,
                            unsigned short* __restrict__ out, int NCtot, int coff) {
    int idx = blockIdx.x * blockDim.x + threadIdx.x;
    if (idx >= K * NCsrc) return;
    int k = idx / NCsrc, j = idx - k * NCsrc;
    int s = k >> 5, kk = k & 31;
    out[(size_t)s * NCtot * 32 + (size_t)(coff + j) * 32 + kk] = f2bf_bits(W[idx]);
}

// ---------------- SpMM (bf16), 4-way edge ILP ---------------------------------
// wave = 1 node; lane = (g, l16): g = edge stream 0..3, l16 covers 8 channels.
__global__ __launch_bounds__(256) void spmm_bf16_ilp(
    const int* __restrict__ row_ptr, const int* __restrict__ col,
    const float* __restrict__ w, const unsigned short* __restrict__ hbf,
    unsigned short* __restrict__ hsbf, int N)
{
    int v = blockIdx.x * 4 + (threadIdx.x >> 6);
    int lane = threadIdx.x & 63;
    int g = lane >> 4;
    int l16 = lane & 15;
    if (v >= N) return;
    int e0 = row_ptr[v], e1 = row_ptr[v + 1];
    float acc[8] = {};
    for (int e = e0 + g; e < e1; e += 4) {
        int cc = col[e];
        float we = w[e];
        const uint4 hv = *reinterpret_cast<const uint4*>(hbf + (size_t)cc * NHID + l16 * 8);
        acc[0] += we * bf_bits2f((unsigned short)hv.x);
        acc[1] += we * bf_bits2f((unsigned short)(hv.x >> 16));
        acc[2] += we * bf_bits2f((unsigned short)hv.y);
        acc[3] += we * bf_bits2f((unsigned short)(hv.y >> 16));
        acc[4] += we * bf_bits2f((unsigned short)hv.z);
        acc[5] += we * bf_bits2f((unsigned short)(hv.z >> 16));
        acc[6] += we * bf_bits2f((unsigned short)hv.w);
        acc[7] += we * bf_bits2f((unsigned short)(hv.w >> 16));
    }
    #pragma unroll
    for (int q = 0; q < 8; q++) {
        acc[q] += __shfl_xor(acc[q], 16, 64);
        acc[q] += __shfl_xor(acc[q], 32, 64);
    }
    if (g == 0) {
        uint4 o;
        o.x = (unsigned int)f2bf_bits(acc[0]) | ((unsigned int)f2bf_bits(acc[1]) << 16);
        o.y = (unsigned int)f2bf_bits(acc[2]) | ((unsigned int)f2bf_bits(acc[3]) << 16);
        o.z = (unsigned int)f2bf_bits(acc[4]) | ((unsigned int)f2bf_bits(acc[5]) << 16);
        o.w = (unsigned int)f2bf_bits(acc[6]) | ((unsigned int)f2bf_bits(acc[7]) << 16);
        *reinterpret_cast<uint4*>(hsbf + (size_t)v * NHID + l16 * 8) = o;
    }
}

// ---------------- fused bf16-MFMA gate GEMM + GRU update ----------------------
__global__ __launch_bounds__(256) void gate_mfma_gru(
    const float* __restrict__ inputs, const unsigned short* __restrict__ hsbf,
    float* __restrict__ h, unsigned short* __restrict__ hbf,
    const unsigned short* __restrict__ WB, const float* __restrict__ bcat, int M)
{
    __shared__ unsigned short As[64 * 40];
    __shared__ unsigned short Bs[512 * 40];
    __shared__ float bcs[512];

    const int tid = threadIdx.x;
    const int wid = tid >> 6;
    const int lane = tid & 63;
    const int row0 = blockIdx.x * 64;
    const int l15 = lane & 15;
    const int lhi = lane >> 4;

    for (int i = tid; i < 512; i += 256) bcs[i] = bcat[i];

    f32x4 acc[4][2][4] = {};

    const int ar = tid >> 2;
    const int aq = tid & 3;
    const int agr = row0 + ar;

    for (int s = 0; s < 16; s++) {
        {
            short8x va = short8x(0);
            if (agr < M) {
                if (s < 8) {
                    const float* src = inputs + (size_t)agr * 256 + s * 32 + aq * 8;
                    const float4 f0 = *reinterpret_cast<const float4*>(src);
                    const float4 f1 = *reinterpret_cast<const float4*>(src + 4);
                    va[0] = (short)f2bf_bits(f0.x); va[1] = (short)f2bf_bits(f0.y);
                    va[2] = (short)f2bf_bits(f0.z); va[3] = (short)f2bf_bits(f0.w);
                    va[4] = (short)f2bf_bits(f1.x); va[5] = (short)f2bf_bits(f1.y);
                    va[6] = (short)f2bf_bits(f1.z); va[7] = (short)f2bf_bits(f1.w);
                } else if (s < 12) {
                    va = *reinterpret_cast<const short8x*>(hbf + (size_t)agr * 128 + (s - 8) * 32 + aq * 8);
                } else {
                    va = *reinterpret_cast<const short8x*>(hsbf + (size_t)agr * 128 + (s - 12) * 32 + aq * 8);
                }
            }
            *reinterpret_cast<short8x*>(&As[ar * 40 + aq * 8]) = va;
        }
        {
            const unsigned short* wbs = WB + (size_t)s * 16384;
            #pragma unroll
            for (int i = 0; i < 8; i++) {
                int id = tid + i * 256;
                int c = id >> 2, q = id & 3;
                short8x vb = *reinterpret_cast<const short8x*>(wbs + id * 8);
                *reinterpret_cast<short8x*>(&Bs[c * 40 + q * 8]) = vb;
            }
        }
        __syncthreads();

        short8x a[4];
        #pragma unroll
        for (int rb = 0; rb < 4; rb++)
            a[rb] = *reinterpret_cast<const short8x*>(&As[(16 * rb + l15) * 40 + lhi * 8]);
        #pragma unroll
        for (int p = 0; p < 4; p++) {
            #pragma unroll
            for (int cb = 0; cb < 2; cb++) {
                int c0 = 128 * p + 32 * wid + 16 * cb + l15;
                short8x b = *reinterpret_cast<const short8x*>(&Bs[c0 * 40 + lhi * 8]);
                #pragma unroll
                for (int rb = 0; rb < 4; rb++)
                    acc[p][cb][rb] = __builtin_amdgcn_mfma_f32_16x16x32_bf16(a[rb], b, acc[p][cb][rb], 0, 0, 0);
            }
        }
        __syncthreads();
    }

    #pragma unroll
    for (int rb = 0; rb < 4; rb++) {
        #pragma unroll
        for (int cb = 0; cb < 2; cb++) {
            int c = 32 * wid + 16 * cb + l15;
            #pragma unroll
            for (int j = 0; j < 4; j++) {
                int row = row0 + 16 * rb + lhi * 4 + j;
                if (row < M) {
                    float g_r  = acc[0][cb][rb][j] + bcs[c];
                    float g_i  = acc[1][cb][rb][j] + bcs[128 + c];
                    float g_n  = acc[2][cb][rb][j];
                    float g_in = acc[3][cb][rb][j] + bcs[384 + c];
                    float rr = sigmoidf_(g_r);
                    float ii = sigmoidf_(g_i);
                    float nn = tanhf(g_in + rr * g_n);
                    size_t o = (size_t)row * 128 + c;
                    float hnew = (1.f - ii) * nn + ii * h[o];
                    h[o] = hnew;
                    hbf[o] = f2bf_bits(hnew);
                }
            }
        }
    }
}

// ---------------- generic MFMA GEMM: C = act(X@W + bias), K=128 ---------------
// X f32 [M x 128] (converted in-flight), W pre-packed bf16 K-step-major.
template<int NC, bool RELU, bool BF16OUT>
__global__ __launch_bounds__(256) void mfma_gemm128(
    const float* __restrict__ X, const unsigned short* __restrict__ WBx,
    const float* __restrict__ bias, void* __restrict__ C, int M)
{
    constexpr int NCW = NC / 4;     // cols per wave
    constexpr int CB = NCW / 16;    // 16-col blocks per wave
    __shared__ unsigned short As[64 * 40];
    __shared__ unsigned short Bs[NC * 40];

    const int tid = threadIdx.x;
    const int wid = tid >> 6;
    const int lane = tid & 63;
    const int l15 = lane & 15;
    const int lhi = lane >> 4;
    const int row0 = blockIdx.x * 64;

    f32x4 acc[CB][4] = {};

    const int ar = tid >> 2;
    const int aq = tid & 3;
    const int agr = row0 + ar;

    for (int s = 0; s < 4; s++) {
        {
            short8x va = short8x(0);
            if (agr < M) {
                const float* src = X + (size_t)agr * 128 + s * 32 + aq * 8;
                const float4 f0 = *reinterpret_cast<const float4*>(src);
                const float4 f1 = *reinterpret_cast<const float4*>(src + 4);
                va[0] = (short)f2bf_bits(f0.x); va[1] = (short)f2bf_bits(f0.y);
                va[2] = (short)f2bf_bits(f0.z); va[3] = (short)f2bf_bits(f0.w);
                va[4] = (short)f2bf_bits(f1.x); va[5] = (short)f2bf_bits(f1.y);
                va[6] = (short)f2bf_bits(f1.z); va[7] = (short)f2bf_bits(f1.w);
            }
            *reinterpret_cast<short8x*>(&As[ar * 40 + aq * 8]) = va;
        }
        {
            const unsigned short* wbs = WBx + (size_t)s * NC * 32;
            #pragma unroll
            for (int i = 0; i < NC / 64; i++) {
                int id = tid + i * 256;           // 0..NC*4-1
                int c = id >> 2, q = id & 3;
                short8x vb = *reinterpret_cast<const short8x*>(wbs + id * 8);
                *reinterpret_cast<short8x*>(&Bs[c * 40 + q * 8]) = vb;
            }
        }
        __syncthreads();

        short8x a[4];
        #pragma unroll
        for (int rb = 0; rb < 4; rb++)
            a[rb] = *reinterpret_cast<const short8x*>(&As[(16 * rb + l15) * 40 + lhi * 8]);
        #pragma unroll
        for (int cb = 0; cb < CB; cb++) {
            int c0 = NCW * wid + 16 * cb + l15;
            short8x b = *reinterpret_cast<const short8x*>(&Bs[c0 * 40 + lhi * 8]);
            #pragma unroll
            for (int rb = 0; rb < 4; rb++)
                acc[cb][rb] = __builtin_amdgcn_mfma_f32_16x16x32_bf16(a[rb], b, acc[cb][rb], 0, 0, 0);
        }
        __syncthreads();
    }

    #pragma unroll
    for (int cb = 0; cb < CB; cb++) {
        int c = NCW * wid + 16 * cb + l15;
        float bv = bias ? bias[c] : 0.f;
        #pragma unroll
        for (int rb = 0; rb < 4; rb++) {
            #pragma unroll
            for (int j = 0; j < 4; j++) {
                int row = row0 + 16 * rb + lhi * 4 + j;
                if (row < M) {
                    float v = acc[cb][rb][j] + bv;
                    if (RELU) v = fmaxf(v, 0.f);
                    size_t o = (size_t)row * NC + c;
                    if (BF16OUT) ((unsigned short*)C)[o] = f2bf_bits(v);
                    else         ((float*)C)[o] = v;
                }
            }
        }
    }
}

// ---------------- LayerNorm (torch variant) -> f32 z out ----------------------
__global__ __launch_bounds__(256) void layernorm_kernel(
    const float* __restrict__ x, const float* __restrict__ gamma,
    const float* __restrict__ beta, float* __restrict__ zout, int N)
{
    int v = blockIdx.x * 4 + (threadIdx.x >> 6);
    int lane = threadIdx.x & 63;
    if (v >= N) return;
    const float* xr = x + (size_t)v * NHID;
    float x0 = xr[lane], x1 = xr[lane + 64];
    float s = x0 + x1;
    #pragma unroll
    for (int off = 32; off; off >>= 1) s += __shfl_xor(s, off, 64);
    float mean = s * (1.f / 128.f);
    float d0 = x0 - mean, d1 = x1 - mean;
    float vs = d0 * d0 + d1 * d1;
    #pragma unroll
    for (int off = 32; off; off >>= 1) vs += __shfl_xor(vs, off, 64);
    float std_ = sqrtf(vs / 127.f);
    float inv = 1.f / (std_ + 1e-6f);
    size_t o = (size_t)v * NHID;
    zout[o + lane] = gamma[lane] * d0 * inv + beta[lane];
    zout[o + lane + 64] = gamma[lane + 64] * d1 * inv + beta[lane + 64];
}

// ---------------- pair decoder, UV interleaved [M][256] -----------------------
__global__ __launch_bounds__(256) void decoder_pairs(
    const unsigned short* __restrict__ UV,
    const int* __restrict__ xi, const int* __restrict__ yi,
    const float* __restrict__ bd1, const float* __restrict__ Wd2,
    const float* __restrict__ bd2, float* __restrict__ dout, int P)
{
    __shared__ float b1s[128], w2s[128];
    if (threadIdx.x < 128) {
        b1s[threadIdx.x] = bd1[threadIdx.x];
        w2s[threadIdx.x] = Wd2[threadIdx.x];
    }
    __syncthreads();
    int p = blockIdx.x * 256 + threadIdx.x;
    if (p >= P) return;
    const unsigned short* ur = UV + (size_t)xi[p] * 256;
    const unsigned short* vr = UV + (size_t)yi[p] * 256 + 128;
    float part = 0.f;
    #pragma unroll
    for (int j0 = 0; j0 < 128; j0 += 8) {
        const uint4 ua = *reinterpret_cast<const uint4*>(ur + j0);
        const uint4 va = *reinterpret_cast<const uint4*>(vr + j0);
        float uf[8], vf[8];
        uf[0] = bf_bits2f((unsigned short)ua.x); uf[1] = bf_bits2f((unsigned short)(ua.x >> 16));
        uf[2] = bf_bits2f((unsigned short)ua.y); uf[3] = bf_bits2f((unsigned short)(ua.y >> 16));
        uf[4] = bf_bits2f((unsigned short)ua.z); uf[5] = bf_bits2f((unsigned short)(ua.z >> 16));
        uf[6] = bf_bits2f((unsigned short)ua.w); uf[7] = bf_bits2f((unsigned short)(ua.w >> 16));
        vf[0] = bf_bits2f((unsigned short)va.x); vf[1] = bf_bits2f((unsigned short)(va.x >> 16));
        vf[2] = bf_bits2f((unsigned short)va.y); vf[3] = bf_bits2f((unsigned short)(va.y >> 16));
        vf[4] = bf_bits2f((unsigned short)va.z); vf[5] = bf_bits2f((unsigned short)(va.z >> 16));
        vf[6] = bf_bits2f((unsigned short)va.w); vf[7] = bf_bits2f((unsigned short)(va.w >> 16));
        #pragma unroll
        for (int q = 0; q < 8; q++) {
            float t = uf[q] + vf[q] + b1s[j0 + q];
            part += fmaxf(t, 0.f) * w2s[j0 + q];
        }
    }
    dout[p] = sigmoidf_(part + bd2[0]);
}

// ---------------- launcher ----------------------------------------------------
extern "C" void kernel_launch(void* const* d_in, const int* in_sizes, int n_in,
                              void* d_out, int out_size, void* d_ws, size_t ws_size,
                              hipStream_t stream) {
    const float* inputs = (const float*)d_in[0];
    const int* edge_row = (const int*)d_in[1];
    const int* edge_col = (const int*)d_in[2];
    const float* edge_w = (const float*)d_in[3];
    const int* x_idx = (const int*)d_in[4];
    const int* y_idx = (const int*)d_in[5];
    const float* Wr_in = (const float*)d_in[6];  const float* br_in = (const float*)d_in[7];
    const float* Wi_in = (const float*)d_in[8];  const float* bi_in = (const float*)d_in[9];
    const float* Wn_in = (const float*)d_in[10]; const float* bn_in = (const float*)d_in[11];
    const float* Hr_self = (const float*)d_in[12]; const float* Hr_nb = (const float*)d_in[13];
    const float* Hi_self = (const float*)d_in[14]; const float* Hi_nb = (const float*)d_in[15];
    const float* Hh_self = (const float*)d_in[16]; const float* Hh_nb = (const float*)d_in[17];
    const float* W1 = (const float*)d_in[18]; const float* b1 = (const float*)d_in[19];
    const float* W2 = (const float*)d_in[20]; const float* b2 = (const float*)d_in[21];
    const float* W3 = (const float*)d_in[22]; const float* b3 = (const float*)d_in[23];
    const float* gamma = (const float*)d_in[24]; const float* beta = (const float*)d_in[25];
    const float* Wd1 = (const float*)d_in[26]; const float* bd1 = (const float*)d_in[27];
    const float* Wd2 = (const float*)d_in[28]; const float* bd2 = (const float*)d_in[29];

    float* out_d = (float*)d_out;            // [P]
    float* out_z = ((float*)d_out) + NPAIR;  // [N*128]

    // ---- workspace layout (~103.7 MB, proven fit) ----
    char* base = (char*)d_ws;
    size_t off = 0;
    auto take = [&](size_t bytes) { void* p = base + off; off = (off + bytes + 255) & ~(size_t)255; return p; };
    int*            row_ptr = (int*)           take((size_t)(N_NODES + 1) * 4);
    unsigned short* WB      = (unsigned short*)take((size_t)512 * 512 * 2);
    float*          bcat    = (float*)         take(512 * 4);
    unsigned short* WB1     = (unsigned short*)take((size_t)128 * 128 * 2);
    unsigned short* WB2     = (unsigned short*)take((size_t)128 * 128 * 2);
    unsigned short* WB3     = (unsigned short*)take((size_t)128 * 128 * 2);
    unsigned short* WBd     = (unsigned short*)take((size_t)256 * 128 * 2);
    float*          h       = (float*)         take((size_t)N_NODES * NHID * 4);
    unsigned short* hbf     = (unsigned short*)take((size_t)N_NODES * NHID * 2);
    unsigned short* hsbf    = (unsigned short*)take((size_t)N_NODES * NHID * 2);
    if (off > ws_size) return;   // diagnostic marker: d stays 0 -> absmax == 0.586

    float* bufC = (float*)hbf;   // 51.2 MB f32 view of hbf+hsbf (post-recurrence)

    // 1. CSR row_ptr
    build_row_ptr<<<(N_NODES + 256) / 256, 256, 0, stream>>>(edge_row, NEDGE, N_NODES, row_ptr);
    // 2. pack weights
    pack_wb<<<(512 * 512 + 255) / 256, 256, 0, stream>>>(
        Wr_in, br_in, Wi_in, bi_in, Wn_in, bn_in,
        Hr_self, Hi_self, Hh_self, Hr_nb, Hi_nb, Hh_nb, WB, bcat);
    pack_kmajor<<<64, 256, 0, stream>>>(W1, 128, 128, WB1, 128, 0);
    pack_kmajor<<<64, 256, 0, stream>>>(W2, 128, 128, WB2, 128, 0);
    pack_kmajor<<<64, 256, 0, stream>>>(W3, 128, 128, WB3, 128, 0);
    pack_kmajor<<<64, 256, 0, stream>>>(Wd1,             128, 128, WBd, 256, 0);
    pack_kmajor<<<64, 256, 0, stream>>>(Wd1 + 128 * 128, 128, 128, WBd, 256, 128);
    // 3. h = 0 (f32 + bf16 mirror)
    {
        long long n = (long long)N_NODES * NHID;
        zero_state<<<(unsigned)((n + 255) / 256), 256, 0, stream>>>(h, hbf, n);
    }
    // 4. recurrent steps
    for (int s = 0; s < NSTEPS; s++) {
        spmm_bf16_ilp<<<(N_NODES + 3) / 4, 256, 0, stream>>>(row_ptr, edge_col, edge_w, hbf, hsbf, N_NODES);
        gate_mfma_gru<<<(N_NODES + 63) / 64, 256, 0, stream>>>(inputs, hsbf, h, hbf, WB, bcat, N_NODES);
    }
    // 5. MLP via MFMA: h -> x1(bufC) -> x2(h) -> x3(bufC)
    {
        int grid = (N_NODES + 63) / 64;
        mfma_gemm128<128, true, false><<<grid, 256, 0, stream>>>(h,    WB1, b1, bufC, N_NODES);
        mfma_gemm128<128, true, false><<<grid, 256, 0, stream>>>(bufC, WB2, b2, h,    N_NODES);
        mfma_gemm128<128, true, false><<<grid, 256, 0, stream>>>(h,    WB3, b3, bufC, N_NODES);
    }
    // 6. LayerNorm: x3(bufC) -> f32 z directly in d_out
    layernorm_kernel<<<(N_NODES + 3) / 4, 256, 0, stream>>>(bufC, gamma, beta, out_z, N_NODES);
    // 7. UV = z @ [Wd1_top | Wd1_bot]  (bf16 [M][256] into h region)
    {
        unsigned short* UV = (unsigned short*)h;
        int grid = (N_NODES + 63) / 64;
        mfma_gemm128<256, false, true><<<grid, 256, 0, stream>>>(out_z, WBd, nullptr, UV, N_NODES);
        // 8. pair decoder -> d (f32)
        decoder_pairs<<<(NPAIR + 255) / 256, 256, 0, stream>>>(
            UV, x_idx, y_idx, bd1, Wd2, bd2, out_d, NPAIR);
    }
}

// Round 7
// 1482.530 us; speedup vs baseline: 4.6173x; 1.2641x over previous
//
#include <hip/hip_runtime.h>
#include <hip/hip_bf16.h>

#define N_NODES 100000
#define NFEAT 256
#define NHID 128
#define NEDGE 3200000
#define NPAIR 200000
#define NSTEPS 5

typedef __attribute__((ext_vector_type(8))) short short8x;   // 8 bf16 (4 VGPR)
typedef __attribute__((ext_vector_type(4))) float f32x4;

__device__ __forceinline__ float sigmoidf_(float x) {
    return 1.f / (1.f + __expf(-x));
}
__device__ __forceinline__ unsigned short f2bf_bits(float f) {
    union { float f; unsigned int u; } c; c.f = f;
    unsigned int r = (c.u + 0x7FFFu + ((c.u >> 16) & 1u)) >> 16;
    return (unsigned short)r;
}
__device__ __forceinline__ float bf_bits2f(unsigned short b) {
    union { float f; unsigned int u; } c; c.u = ((unsigned int)b) << 16;
    return c.f;
}
// conflict-free LDS chunk offset (ushorts): row of 32 bf16, chunk q (8 bf16)
__device__ __forceinline__ int swz8(int row, int q) {
    return row * 32 + ((q + (row >> 1)) & 3) * 8;
}

// ---------------- utility ------------------------------------------------------
__global__ void zero_u16(unsigned short* __restrict__ p, long long n) {
    long long i = (long long)blockIdx.x * blockDim.x + threadIdx.x;
    if (i < n) p[i] = 0;
}

__global__ void build_row_ptr(const int* __restrict__ rows, int E, int N, int* __restrict__ row_ptr) {
    int i = blockIdx.x * blockDim.x + threadIdx.x;
    if (i > N) return;
    int lo = 0, hi = E;
    while (lo < hi) {
        int mid = (lo + hi) >> 1;
        if (rows[mid] < i) lo = mid + 1; else hi = mid;
    }
    row_ptr[i] = lo;
}

// pack f32 [K x NCsrc] into bf16 K-step-major [ (k+koff)/32 ][ coff+j ][ (k+koff)%32 ]
__global__ void pack_kmajor(const float* __restrict__ W, int K, int NCsrc,
                            unsigned short* __restrict__ out, int NCtot, int coff, int koff) {
    int idx = blockIdx.x * blockDim.x + threadIdx.x;
    if (idx >= K * NCsrc) return;
    int k = idx / NCsrc, j = idx - k * NCsrc;
    int kg = k + koff;
    out[(size_t)(kg >> 5) * NCtot * 32 + (size_t)(coff + j) * 32 + (kg & 31)] = f2bf_bits(W[idx]);
}

__global__ void pack_bin(const float* __restrict__ br, const float* __restrict__ bi,
                         const float* __restrict__ bn, float* __restrict__ bin) {
    int i = blockIdx.x * blockDim.x + threadIdx.x;
    if (i >= 384) return;
    bin[i] = (i < 128) ? br[i] : (i < 256) ? bi[i - 128] : bn[i - 256];
}

// ---------------- SpMM (bf16), 4 edge streams x 2 unroll ----------------------
__global__ __launch_bounds__(256) void spmm_bf16_ilp(
    const int* __restrict__ row_ptr, const int* __restrict__ col,
    const float* __restrict__ w, const unsigned short* __restrict__ hbf,
    unsigned short* __restrict__ hsbf, int N)
{
    int v = blockIdx.x * 4 + (threadIdx.x >> 6);
    int lane = threadIdx.x & 63;
    int g = lane >> 4;
    int l16 = lane & 15;
    if (v >= N) return;
    int e0 = row_ptr[v], e1 = row_ptr[v + 1];
    float acc[8] = {};
    int e = e0 + g;
    for (; e + 4 < e1; e += 8) {
        int c1 = col[e], c2 = col[e + 4];
        float w1 = w[e], w2 = w[e + 4];
        const uint4 h1 = *reinterpret_cast<const uint4*>(hbf + (size_t)c1 * NHID + l16 * 8);
        const uint4 h2 = *reinterpret_cast<const uint4*>(hbf + (size_t)c2 * NHID + l16 * 8);
        acc[0] += w1 * bf_bits2f((unsigned short)h1.x) + w2 * bf_bits2f((unsigned short)h2.x);
        acc[1] += w1 * bf_bits2f((unsigned short)(h1.x >> 16)) + w2 * bf_bits2f((unsigned short)(h2.x >> 16));
        acc[2] += w1 * bf_bits2f((unsigned short)h1.y) + w2 * bf_bits2f((unsigned short)h2.y);
        acc[3] += w1 * bf_bits2f((unsigned short)(h1.y >> 16)) + w2 * bf_bits2f((unsigned short)(h2.y >> 16));
        acc[4] += w1 * bf_bits2f((unsigned short)h1.z) + w2 * bf_bits2f((unsigned short)h2.z);
        acc[5] += w1 * bf_bits2f((unsigned short)(h1.z >> 16)) + w2 * bf_bits2f((unsigned short)(h2.z >> 16));
        acc[6] += w1 * bf_bits2f((unsigned short)h1.w) + w2 * bf_bits2f((unsigned short)h2.w);
        acc[7] += w1 * bf_bits2f((unsigned short)(h1.w >> 16)) + w2 * bf_bits2f((unsigned short)(h2.w >> 16));
    }
    for (; e < e1; e += 4) {
        int cc = col[e];
        float we = w[e];
        const uint4 hv = *reinterpret_cast<const uint4*>(hbf + (size_t)cc * NHID + l16 * 8);
        acc[0] += we * bf_bits2f((unsigned short)hv.x);
        acc[1] += we * bf_bits2f((unsigned short)(hv.x >> 16));
        acc[2] += we * bf_bits2f((unsigned short)hv.y);
        acc[3] += we * bf_bits2f((unsigned short)(hv.y >> 16));
        acc[4] += we * bf_bits2f((unsigned short)hv.z);
        acc[5] += we * bf_bits2f((unsigned short)(hv.z >> 16));
        acc[6] += we * bf_bits2f((unsigned short)hv.w);
        acc[7] += we * bf_bits2f((unsigned short)(hv.w >> 16));
    }
    #pragma unroll
    for (int q = 0; q < 8; q++) {
        acc[q] += __shfl_xor(acc[q], 16, 64);
        acc[q] += __shfl_xor(acc[q], 32, 64);
    }
    if (g == 0) {
        uint4 o;
        o.x = (unsigned int)f2bf_bits(acc[0]) | ((unsigned int)f2bf_bits(acc[1]) << 16);
        o.y = (unsigned int)f2bf_bits(acc[2]) | ((unsigned int)f2bf_bits(acc[3]) << 16);
        o.z = (unsigned int)f2bf_bits(acc[4]) | ((unsigned int)f2bf_bits(acc[5]) << 16);
        o.w = (unsigned int)f2bf_bits(acc[6]) | ((unsigned int)f2bf_bits(acc[7]) << 16);
        *reinterpret_cast<uint4*>(hsbf + (size_t)v * NHID + l16 * 8) = o;
    }
}

// ---------------- per-step gate GEMM (K=256) + GRU, h bf16 in place -----------
// A = [hbf(128) | hsbf(128)]; B = Hcat 256x384 [r|i|gcn_n]; IN bf16 [N][384].
__global__ __launch_bounds__(256, 3) void gate_step_mfma(
    const unsigned short* __restrict__ hsbf, unsigned short* __restrict__ hbf,
    const unsigned short* __restrict__ IN, const unsigned short* __restrict__ WBg, int M)
{
    __shared__ unsigned short As[64 * 32];
    __shared__ unsigned short Bs[384 * 32];

    const int tid = threadIdx.x;
    const int wid = tid >> 6;
    const int lane = tid & 63;
    const int row0 = blockIdx.x * 64;
    const int l15 = lane & 15;
    const int lhi = lane >> 4;

    f32x4 acc[3][2][4] = {};

    const int ar = tid >> 2;
    const int aq = tid & 3;
    const int agr = row0 + ar;

    for (int s = 0; s < 8; s++) {
        {
            short8x va = short8x(0);
            if (agr < M) {
                const unsigned short* src = (s < 4)
                    ? (hbf  + (size_t)agr * 128 + s * 32)
                    : (hsbf + (size_t)agr * 128 + (s - 4) * 32);
                va = *reinterpret_cast<const short8x*>(src + aq * 8);
            }
            *reinterpret_cast<short8x*>(&As[swz8(ar, aq)]) = va;
        }
        {
            const unsigned short* wbs = WBg + (size_t)s * 384 * 32;
            #pragma unroll
            for (int i = 0; i < 6; i++) {
                int id = tid + i * 256;
                int c = id >> 2, q = id & 3;
                short8x vb = *reinterpret_cast<const short8x*>(wbs + id * 8);
                *reinterpret_cast<short8x*>(&Bs[swz8(c, q)]) = vb;
            }
        }
        __syncthreads();

        short8x a[4];
        #pragma unroll
        for (int rb = 0; rb < 4; rb++)
            a[rb] = *reinterpret_cast<const short8x*>(&As[swz8(16 * rb + l15, lhi)]);
        #pragma unroll
        for (int p = 0; p < 3; p++) {
            #pragma unroll
            for (int cb = 0; cb < 2; cb++) {
                int c0 = 128 * p + 32 * wid + 16 * cb + l15;
                short8x b = *reinterpret_cast<const short8x*>(&Bs[swz8(c0, lhi)]);
                #pragma unroll
                for (int rb = 0; rb < 4; rb++)
                    acc[p][cb][rb] = __builtin_amdgcn_mfma_f32_16x16x32_bf16(a[rb], b, acc[p][cb][rb], 0, 0, 0);
            }
        }
        __syncthreads();
    }

    // GRU epilogue (thread-local gates; IN holds in_r,in_i,in_n incl. biases)
    #pragma unroll
    for (int rb = 0; rb < 4; rb++) {
        #pragma unroll
        for (int cb = 0; cb < 2; cb++) {
            int c = 32 * wid + 16 * cb + l15;
            #pragma unroll
            for (int j = 0; j < 4; j++) {
                int row = row0 + 16 * rb + lhi * 4 + j;
                if (row < M) {
                    size_t ib = (size_t)row * 384;
                    float g_r = acc[0][cb][rb][j] + bf_bits2f(IN[ib + c]);
                    float g_i = acc[1][cb][rb][j] + bf_bits2f(IN[ib + 128 + c]);
                    float inn = bf_bits2f(IN[ib + 256 + c]);
                    float rr = sigmoidf_(g_r);
                    float ii = sigmoidf_(g_i);
                    float nn = tanhf(inn + rr * acc[2][cb][rb][j]);
                    size_t o = (size_t)row * 128 + c;
                    float hold = bf_bits2f(hbf[o]);
                    hbf[o] = f2bf_bits((1.f - ii) * nn + ii * hold);
                }
            }
        }
    }
}

// ---------------- generic MFMA GEMM: C = act(X@W + bias) ----------------------
// X: f32 (converted in flight) or bf16, row-major [M x K]; W pre-packed k-major.
template<int K, int NC, bool F32IN, bool RELU, bool BF16OUT>
__global__ __launch_bounds__(256, 3) void mfma_gemm(
    const void* __restrict__ Xv, const unsigned short* __restrict__ WBx,
    const float* __restrict__ bias, void* __restrict__ C, int M)
{
    constexpr int KS = K / 32;
    constexpr int BI = NC / 64;
    constexpr int NCW = NC / 4;
    constexpr int CB = NCW / 16;
    __shared__ unsigned short As[64 * 32];
    __shared__ unsigned short Bs[NC * 32];

    const int tid = threadIdx.x;
    const int wid = tid >> 6;
    const int lane = tid & 63;
    const int l15 = lane & 15;
    const int lhi = lane >> 4;
    const int row0 = blockIdx.x * 64;

    f32x4 acc[CB][4] = {};

    const int ar = tid >> 2;
    const int aq = tid & 3;
    const int agr = row0 + ar;

    for (int s = 0; s < KS; s++) {
        {
            short8x va = short8x(0);
            if (agr < M) {
                if (F32IN) {
                    const float* src = (const float*)Xv + (size_t)agr * K + s * 32 + aq * 8;
                    const float4 f0 = *reinterpret_cast<const float4*>(src);
                    const float4 f1 = *reinterpret_cast<const float4*>(src + 4);
                    va[0] = (short)f2bf_bits(f0.x); va[1] = (short)f2bf_bits(f0.y);
                    va[2] = (short)f2bf_bits(f0.z); va[3] = (short)f2bf_bits(f0.w);
                    va[4] = (short)f2bf_bits(f1.x); va[5] = (short)f2bf_bits(f1.y);
                    va[6] = (short)f2bf_bits(f1.z); va[7] = (short)f2bf_bits(f1.w);
                } else {
                    va = *reinterpret_cast<const short8x*>(
                        (const unsigned short*)Xv + (size_t)agr * K + s * 32 + aq * 8);
                }
            }
            *reinterpret_cast<short8x*>(&As[swz8(ar, aq)]) = va;
        }
        {
            const unsigned short* wbs = WBx + (size_t)s * NC * 32;
            #pragma unroll
            for (int i = 0; i < BI; i++) {
                int id = tid + i * 256;
                int c = id >> 2, q = id & 3;
                short8x vb = *reinterpret_cast<const short8x*>(wbs + id * 8);
                *reinterpret_cast<short8x*>(&Bs[swz8(c, q)]) = vb;
            }
        }
        __syncthreads();

        short8x a[4];
        #pragma unroll
        for (int rb = 0; rb < 4; rb++)
            a[rb] = *reinterpret_cast<const short8x*>(&As[swz8(16 * rb + l15, lhi)]);
        #pragma unroll
        for (int cb = 0; cb < CB; cb++) {
            int c0 = NCW * wid + 16 * cb + l15;
            short8x b = *reinterpret_cast<const short8x*>(&Bs[swz8(c0, lhi)]);
            #pragma unroll
            for (int rb = 0; rb < 4; rb++)
                acc[cb][rb] = __builtin_amdgcn_mfma_f32_16x16x32_bf16(a[rb], b, acc[cb][rb], 0, 0, 0);
        }
        __syncthreads();
    }

    #pragma unroll
    for (int cb = 0; cb < CB; cb++) {
        int c = NCW * wid + 16 * cb + l15;
        float bv = bias ? bias[c] : 0.f;
        #pragma unroll
        for (int rb = 0; rb < 4; rb++) {
            #pragma unroll
            for (int j = 0; j < 4; j++) {
                int row = row0 + 16 * rb + lhi * 4 + j;
                if (row < M) {
                    float v = acc[cb][rb][j] + bv;
                    if (RELU) v = fmaxf(v, 0.f);
                    size_t o = (size_t)row * NC + c;
                    if (BF16OUT) ((unsigned short*)C)[o] = f2bf_bits(v);
                    else         ((float*)C)[o] = v;
                }
            }
        }
    }
}

// ---------------- LayerNorm (torch variant), bf16 in -> f32 z + bf16 z --------
__global__ __launch_bounds__(256) void layernorm_bf(
    const unsigned short* __restrict__ x, const float* __restrict__ gamma,
    const float* __restrict__ beta, float* __restrict__ zout,
    unsigned short* __restrict__ zbf, int N)
{
    int v = blockIdx.x * 4 + (threadIdx.x >> 6);
    int lane = threadIdx.x & 63;
    if (v >= N) return;
    const unsigned short* xr = x + (size_t)v * NHID;
    float x0 = bf_bits2f(xr[lane]), x1 = bf_bits2f(xr[lane + 64]);
    float s = x0 + x1;
    #pragma unroll
    for (int off = 32; off; off >>= 1) s += __shfl_xor(s, off, 64);
    float mean = s * (1.f / 128.f);
    float d0 = x0 - mean, d1 = x1 - mean;
    float vs = d0 * d0 + d1 * d1;
    #pragma unroll
    for (int off = 32; off; off >>= 1) vs += __shfl_xor(vs, off, 64);
    float std_ = sqrtf(vs / 127.f);
    float inv = 1.f / (std_ + 1e-6f);
    float z0 = gamma[lane] * d0 * inv + beta[lane];
    float z1 = gamma[lane + 64] * d1 * inv + beta[lane + 64];
    size_t o = (size_t)v * NHID;
    zout[o + lane] = z0;
    zout[o + lane + 64] = z1;
    zbf[o + lane] = f2bf_bits(z0);
    zbf[o + lane + 64] = f2bf_bits(z1);
}

// ---------------- pair decoder, UV interleaved [M][256] -----------------------
__global__ __launch_bounds__(256) void decoder_pairs(
    const unsigned short* __restrict__ UV,
    const int* __restrict__ xi, const int* __restrict__ yi,
    const float* __restrict__ bd1, const float* __restrict__ Wd2,
    const float* __restrict__ bd2, float* __restrict__ dout, int P)
{
    __shared__ float b1s[128], w2s[128];
    if (threadIdx.x < 128) {
        b1s[threadIdx.x] = bd1[threadIdx.x];
        w2s[threadIdx.x] = Wd2[threadIdx.x];
    }
    __syncthreads();
    int p = blockIdx.x * 256 + threadIdx.x;
    if (p >= P) return;
    const unsigned short* ur = UV + (size_t)xi[p] * 256;
    const unsigned short* vr = UV + (size_t)yi[p] * 256 + 128;
    float part = 0.f;
    #pragma unroll
    for (int j0 = 0; j0 < 128; j0 += 8) {
        const uint4 ua = *reinterpret_cast<const uint4*>(ur + j0);
        const uint4 va = *reinterpret_cast<const uint4*>(vr + j0);
        float uf[8], vf[8];
        uf[0] = bf_bits2f((unsigned short)ua.x); uf[1] = bf_bits2f((unsigned short)(ua.x >> 16));
        uf[2] = bf_bits2f((unsigned short)ua.y); uf[3] = bf_bits2f((unsigned short)(ua.y >> 16));
        uf[4] = bf_bits2f((unsigned short)ua.z); uf[5] = bf_bits2f((unsigned short)(ua.z >> 16));
        uf[6] = bf_bits2f((unsigned short)ua.w); uf[7] = bf_bits2f((unsigned short)(ua.w >> 16));
        vf[0] = bf_bits2f((unsigned short)va.x); vf[1] = bf_bits2f((unsigned short)(va.x >> 16));
        vf[2] = bf_bits2f((unsigned short)va.y); vf[3] = bf_bits2f((unsigned short)(va.y >> 16));
        vf[4] = bf_bits2f((unsigned short)va.z); vf[5] = bf_bits2f((unsigned short)(va.z >> 16));
        vf[6] = bf_bits2f((unsigned short)va.w); vf[7] = bf_bits2f((unsigned short)(va.w >> 16));
        #pragma unroll
        for (int q = 0; q < 8; q++) {
            float t = uf[q] + vf[q] + b1s[j0 + q];
            part += fmaxf(t, 0.f) * w2s[j0 + q];
        }
    }
    dout[p] = sigmoidf_(part + bd2[0]);
}

// ---------------- launcher ----------------------------------------------------
extern "C" void kernel_launch(void* const* d_in, const int* in_sizes, int n_in,
                              void* d_out, int out_size, void* d_ws, size_t ws_size,
                              hipStream_t stream) {
    const float* inputs = (const float*)d_in[0];
    const int* edge_row = (const int*)d_in[1];
    const int* edge_col = (const int*)d_in[2];
    const float* edge_w = (const float*)d_in[3];
    const int* x_idx = (const int*)d_in[4];
    const int* y_idx = (const int*)d_in[5];
    const float* Wr_in = (const float*)d_in[6];  const float* br_in = (const float*)d_in[7];
    const float* Wi_in = (const float*)d_in[8];  const float* bi_in = (const float*)d_in[9];
    const float* Wn_in = (const float*)d_in[10]; const float* bn_in = (const float*)d_in[11];
    const float* Hr_self = (const float*)d_in[12]; const float* Hr_nb = (const float*)d_in[13];
    const float* Hi_self = (const float*)d_in[14]; const float* Hi_nb = (const float*)d_in[15];
    const float* Hh_self = (const float*)d_in[16]; const float* Hh_nb = (const float*)d_in[17];
    const float* W1 = (const float*)d_in[18]; const float* b1 = (const float*)d_in[19];
    const float* W2 = (const float*)d_in[20]; const float* b2 = (const float*)d_in[21];
    const float* W3 = (const float*)d_in[22]; const float* b3 = (const float*)d_in[23];
    const float* gamma = (const float*)d_in[24]; const float* beta = (const float*)d_in[25];
    const float* Wd1 = (const float*)d_in[26]; const float* bd1 = (const float*)d_in[27];
    const float* Wd2 = (const float*)d_in[28]; const float* bd2 = (const float*)d_in[29];

    float* out_d = (float*)d_out;            // [P]
    float* out_z = ((float*)d_out) + NPAIR;  // [N*128]

    // ---- workspace layout (~129 MB) ----
    char* base = (char*)d_ws;
    size_t off = 0;
    auto take = [&](size_t bytes) { void* p = base + off; off = (off + bytes + 255) & ~(size_t)255; return p; };
    int*            row_ptr = (int*)           take((size_t)(N_NODES + 1) * 4);
    unsigned short* WBg     = (unsigned short*)take((size_t)8 * 384 * 32 * 2);   // Hcat 256x384
    unsigned short* WBin    = (unsigned short*)take((size_t)8 * 384 * 32 * 2);   // Win 256x384
    unsigned short* WB1     = (unsigned short*)take((size_t)4 * 128 * 32 * 2);
    unsigned short* WB2     = (unsigned short*)take((size_t)4 * 128 * 32 * 2);
    unsigned short* WB3     = (unsigned short*)take((size_t)4 * 128 * 32 * 2);
    unsigned short* WBd     = (unsigned short*)take((size_t)4 * 256 * 32 * 2);
    float*          bin     = (float*)         take(384 * 4);
    unsigned short* IN      = (unsigned short*)take((size_t)N_NODES * 384 * 2);  // 76.8 MB; later x2 / UV
    unsigned short* hbf     = (unsigned short*)take((size_t)N_NODES * NHID * 2); // later x3 / zbf
    unsigned short* hsbf    = (unsigned short*)take((size_t)N_NODES * NHID * 2); // later x1 / x3
    if (off > ws_size) return;   // diagnostic marker: d stays 0 -> absmax == 0.586

    // 1. CSR row_ptr
    build_row_ptr<<<(N_NODES + 256) / 256, 256, 0, stream>>>(edge_row, NEDGE, N_NODES, row_ptr);
    // 2. pack all weights (bf16 k-major)
    pack_kmajor<<<64, 256, 0, stream>>>(Hr_self, 128, 128, WBg, 384, 0, 0);
    pack_kmajor<<<64, 256, 0, stream>>>(Hi_self, 128, 128, WBg, 384, 128, 0);
    pack_kmajor<<<64, 256, 0, stream>>>(Hh_self, 128, 128, WBg, 384, 256, 0);
    pack_kmajor<<<64, 256, 0, stream>>>(Hr_nb,   128, 128, WBg, 384, 0, 128);
    pack_kmajor<<<64, 256, 0, stream>>>(Hi_nb,   128, 128, WBg, 384, 128, 128);
    pack_kmajor<<<64, 256, 0, stream>>>(Hh_nb,   128, 128, WBg, 384, 256, 128);
    pack_kmajor<<<128, 256, 0, stream>>>(Wr_in, 256, 128, WBin, 384, 0, 0);
    pack_kmajor<<<128, 256, 0, stream>>>(Wi_in, 256, 128, WBin, 384, 128, 0);
    pack_kmajor<<<128, 256, 0, stream>>>(Wn_in, 256, 128, WBin, 384, 256, 0);
    pack_kmajor<<<64, 256, 0, stream>>>(W1, 128, 128, WB1, 128, 0, 0);
    pack_kmajor<<<64, 256, 0, stream>>>(W2, 128, 128, WB2, 128, 0, 0);
    pack_kmajor<<<64, 256, 0, stream>>>(W3, 128, 128, WB3, 128, 0, 0);
    pack_kmajor<<<64, 256, 0, stream>>>(Wd1,             128, 128, WBd, 256, 0, 0);
    pack_kmajor<<<64, 256, 0, stream>>>(Wd1 + 128 * 128, 128, 128, WBd, 256, 128, 0);
    pack_bin<<<2, 256, 0, stream>>>(br_in, bi_in, bn_in, bin);
    // 3. h = 0 (bf16 master)
    {
        long long n = (long long)N_NODES * NHID;
        zero_u16<<<(unsigned)((n + 255) / 256), 256, 0, stream>>>(hbf, n);
    }
    int grid64 = (N_NODES + 63) / 64;
    // 4. IN = inputs @ [Wr|Wi|Wn] + [br|bi|bn]  (one-time, bf16 [N][384])
    mfma_gemm<256, 384, true, false, true><<<grid64, 256, 0, stream>>>(inputs, WBin, bin, IN, N_NODES);
    // 5. recurrent steps
    for (int s = 0; s < NSTEPS; s++) {
        spmm_bf16_ilp<<<(N_NODES + 3) / 4, 256, 0, stream>>>(row_ptr, edge_col, edge_w, hbf, hsbf, N_NODES);
        gate_step_mfma<<<grid64, 256, 0, stream>>>(hsbf, hbf, IN, WBg, N_NODES);
    }
    // 6. MLP (bf16 chain): hbf -> x1(hsbf) -> x2(IN region) -> x3(hbf region)
    unsigned short* x1 = hsbf;
    unsigned short* x2 = IN;
    unsigned short* x3 = hbf;
    mfma_gemm<128, 128, false, true, true><<<grid64, 256, 0, stream>>>(hbf, WB1, b1, x1, N_NODES);
    mfma_gemm<128, 128, false, true, true><<<grid64, 256, 0, stream>>>(x1, WB2, b2, x2, N_NODES);
    mfma_gemm<128, 128, false, true, true><<<grid64, 256, 0, stream>>>(x2, WB3, b3, x3, N_NODES);
    // 7. LayerNorm: x3 -> f32 z (d_out) + bf16 z (hsbf region)
    unsigned short* zbf = hsbf;
    layernorm_bf<<<(N_NODES + 3) / 4, 256, 0, stream>>>(x3, gamma, beta, out_z, zbf, N_NODES);
    // 8. UV = z @ [Wd1_top | Wd1_bot]  (bf16 [N][256] into IN region)
    unsigned short* UV = IN;
    mfma_gemm<128, 256, false, false, true><<<grid64, 256, 0, stream>>>(zbf, WBd, nullptr, UV, N_NODES);
    // 9. pair decoder -> d (f32)
    decoder_pairs<<<(NPAIR + 255) / 256, 256, 0, stream>>>(
        UV, x_idx, y_idx, bd1, Wd2, bd2, out_d, NPAIR);
}

// Round 8
// 1130.877 us; speedup vs baseline: 6.0531x; 1.3110x over previous
//
#include <hip/hip_runtime.h>
#include <hip/hip_bf16.h>

#define N_NODES 100000
#define NFEAT 256
#define NHID 128
#define NEDGE 3200000
#define NPAIR 200000
#define NSTEPS 5

typedef __attribute__((ext_vector_type(8))) short short8x;   // 8 bf16 (4 VGPR)
typedef __attribute__((ext_vector_type(4))) float f32x4;

__device__ __forceinline__ float sigmoidf_(float x) {
    return 1.f / (1.f + __expf(-x));
}
__device__ __forceinline__ unsigned short f2bf_bits(float f) {
    union { float f; unsigned int u; } c; c.f = f;
    unsigned int r = (c.u + 0x7FFFu + ((c.u >> 16) & 1u)) >> 16;
    return (unsigned short)r;
}
__device__ __forceinline__ float bf_bits2f(unsigned short b) {
    union { float f; unsigned int u; } c; c.u = ((unsigned int)b) << 16;
    return c.f;
}
// conflict-free LDS chunk offset (ushorts): row of 32 bf16, chunk q (8 bf16)
__device__ __forceinline__ int swz8(int row, int q) {
    return row * 32 + ((q + (row >> 1)) & 3) * 8;
}

// ---------------- utility ------------------------------------------------------
__global__ void zero_u16(unsigned short* __restrict__ p, long long n) {
    long long i = (long long)blockIdx.x * blockDim.x + threadIdx.x;
    if (i < n) p[i] = 0;
}

__global__ void build_row_ptr(const int* __restrict__ rows, int E, int N, int* __restrict__ row_ptr) {
    int i = blockIdx.x * blockDim.x + threadIdx.x;
    if (i > N) return;
    int lo = 0, hi = E;
    while (lo < hi) {
        int mid = (lo + hi) >> 1;
        if (rows[mid] < i) lo = mid + 1; else hi = mid;
    }
    row_ptr[i] = lo;
}

// pack f32 [K x NCsrc] into bf16 K-step-major [ (k+koff)/32 ][ coff+j ][ (k+koff)%32 ]
__global__ void pack_kmajor(const float* __restrict__ W, int K, int NCsrc,
                            unsigned short* __restrict__ out, int NCtot, int coff, int koff) {
    int idx = blockIdx.x * blockDim.x + threadIdx.x;
    if (idx >= K * NCsrc) return;
    int k = idx / NCsrc, j = idx - k * NCsrc;
    int kg = k + koff;
    out[(size_t)(kg >> 5) * NCtot * 32 + (size_t)(coff + j) * 32 + (kg & 31)] = f2bf_bits(W[idx]);
}

__global__ void pack_bin(const float* __restrict__ br, const float* __restrict__ bi,
                         const float* __restrict__ bn, float* __restrict__ bin) {
    int i = blockIdx.x * blockDim.x + threadIdx.x;
    if (i >= 384) return;
    bin[i] = (i < 128) ? br[i] : (i < 256) ? bi[i - 128] : bn[i - 256];
}

// ---------------- SpMM (bf16), 4 edge streams x 2 unroll ----------------------
__global__ __launch_bounds__(256) void spmm_bf16_ilp(
    const int* __restrict__ row_ptr, const int* __restrict__ col,
    const float* __restrict__ w, const unsigned short* __restrict__ hbf,
    unsigned short* __restrict__ hsbf, int N)
{
    int v = blockIdx.x * 4 + (threadIdx.x >> 6);
    int lane = threadIdx.x & 63;
    int g = lane >> 4;
    int l16 = lane & 15;
    if (v >= N) return;
    int e0 = row_ptr[v], e1 = row_ptr[v + 1];
    float acc[8] = {};
    int e = e0 + g;
    for (; e + 4 < e1; e += 8) {
        int c1 = col[e], c2 = col[e + 4];
        float w1 = w[e], w2 = w[e + 4];
        const uint4 h1 = *reinterpret_cast<const uint4*>(hbf + (size_t)c1 * NHID + l16 * 8);
        const uint4 h2 = *reinterpret_cast<const uint4*>(hbf + (size_t)c2 * NHID + l16 * 8);
        acc[0] += w1 * bf_bits2f((unsigned short)h1.x) + w2 * bf_bits2f((unsigned short)h2.x);
        acc[1] += w1 * bf_bits2f((unsigned short)(h1.x >> 16)) + w2 * bf_bits2f((unsigned short)(h2.x >> 16));
        acc[2] += w1 * bf_bits2f((unsigned short)h1.y) + w2 * bf_bits2f((unsigned short)h2.y);
        acc[3] += w1 * bf_bits2f((unsigned short)(h1.y >> 16)) + w2 * bf_bits2f((unsigned short)(h2.y >> 16));
        acc[4] += w1 * bf_bits2f((unsigned short)h1.z) + w2 * bf_bits2f((unsigned short)h2.z);
        acc[5] += w1 * bf_bits2f((unsigned short)(h1.z >> 16)) + w2 * bf_bits2f((unsigned short)(h2.z >> 16));
        acc[6] += w1 * bf_bits2f((unsigned short)h1.w) + w2 * bf_bits2f((unsigned short)h2.w);
        acc[7] += w1 * bf_bits2f((unsigned short)(h1.w >> 16)) + w2 * bf_bits2f((unsigned short)(h2.w >> 16));
    }
    for (; e < e1; e += 4) {
        int cc = col[e];
        float we = w[e];
        const uint4 hv = *reinterpret_cast<const uint4*>(hbf + (size_t)cc * NHID + l16 * 8);
        acc[0] += we * bf_bits2f((unsigned short)hv.x);
        acc[1] += we * bf_bits2f((unsigned short)(hv.x >> 16));
        acc[2] += we * bf_bits2f((unsigned short)hv.y);
        acc[3] += we * bf_bits2f((unsigned short)(hv.y >> 16));
        acc[4] += we * bf_bits2f((unsigned short)hv.z);
        acc[5] += we * bf_bits2f((unsigned short)(hv.z >> 16));
        acc[6] += we * bf_bits2f((unsigned short)hv.w);
        acc[7] += we * bf_bits2f((unsigned short)(hv.w >> 16));
    }
    #pragma unroll
    for (int q = 0; q < 8; q++) {
        acc[q] += __shfl_xor(acc[q], 16, 64);
        acc[q] += __shfl_xor(acc[q], 32, 64);
    }
    if (g == 0) {
        uint4 o;
        o.x = (unsigned int)f2bf_bits(acc[0]) | ((unsigned int)f2bf_bits(acc[1]) << 16);
        o.y = (unsigned int)f2bf_bits(acc[2]) | ((unsigned int)f2bf_bits(acc[3]) << 16);
        o.z = (unsigned int)f2bf_bits(acc[4]) | ((unsigned int)f2bf_bits(acc[5]) << 16);
        o.w = (unsigned int)f2bf_bits(acc[6]) | ((unsigned int)f2bf_bits(acc[7]) << 16);
        *reinterpret_cast<uint4*>(hsbf + (size_t)v * NHID + l16 * 8) = o;
    }
}

// ---------------- per-step gate GEMM (K=256) + GRU, h bf16 in place -----------
// A = [hbf(128) | hsbf(128)]; B = Hcat 256x384 [r|i|gcn_n]; IN bf16 [N][384].
// SWAPPED mfma operands: acc row = 16*rb + l15, acc col = 16*cb-block + 4*lhi + j
// -> per-lane 4 consecutive cols of one row: 8B vector loads/stores in epilogue.
__global__ __launch_bounds__(256, 2) void gate_step_mfma(
    const unsigned short* __restrict__ hsbf, unsigned short* __restrict__ hbf,
    const unsigned short* __restrict__ IN, const unsigned short* __restrict__ WBg, int M)
{
    __shared__ unsigned short As[64 * 32];
    __shared__ unsigned short Bs[384 * 32];

    const int tid = threadIdx.x;
    const int wid = tid >> 6;
    const int lane = tid & 63;
    const int row0 = blockIdx.x * 64;
    const int l15 = lane & 15;
    const int lhi = lane >> 4;

    f32x4 acc[3][2][4] = {};

    const int ar = tid >> 2;
    const int aq = tid & 3;
    const int agr = row0 + ar;

    for (int s = 0; s < 8; s++) {
        {
            short8x va = short8x(0);
            if (agr < M) {
                const unsigned short* src = (s < 4)
                    ? (hbf  + (size_t)agr * 128 + s * 32)
                    : (hsbf + (size_t)agr * 128 + (s - 4) * 32);
                va = *reinterpret_cast<const short8x*>(src + aq * 8);
            }
            *reinterpret_cast<short8x*>(&As[swz8(ar, aq)]) = va;
        }
        {
            const unsigned short* wbs = WBg + (size_t)s * 384 * 32;
            #pragma unroll
            for (int i = 0; i < 6; i++) {
                int id = tid + i * 256;
                int c = id >> 2, q = id & 3;
                short8x vb = *reinterpret_cast<const short8x*>(wbs + id * 8);
                *reinterpret_cast<short8x*>(&Bs[swz8(c, q)]) = vb;
            }
        }
        __syncthreads();

        short8x a[4];
        #pragma unroll
        for (int rb = 0; rb < 4; rb++)
            a[rb] = *reinterpret_cast<const short8x*>(&As[swz8(16 * rb + l15, lhi)]);
        #pragma unroll
        for (int p = 0; p < 3; p++) {
            #pragma unroll
            for (int cb = 0; cb < 2; cb++) {
                int c0 = 128 * p + 32 * wid + 16 * cb + l15;
                short8x b = *reinterpret_cast<const short8x*>(&Bs[swz8(c0, lhi)]);
                #pragma unroll
                for (int rb = 0; rb < 4; rb++)
                    acc[p][cb][rb] = __builtin_amdgcn_mfma_f32_16x16x32_bf16(b, a[rb], acc[p][cb][rb], 0, 0, 0);
            }
        }
        __syncthreads();
    }

    // GRU epilogue: per lane, row = row0+16rb+l15, 4 consecutive cols
    #pragma unroll
    for (int rb = 0; rb < 4; rb++) {
        int row = row0 + 16 * rb + l15;
        if (row >= M) continue;
        size_t ib = (size_t)row * 384;
        size_t ob = (size_t)row * 128;
        #pragma unroll
        for (int cb = 0; cb < 2; cb++) {
            int cq = 32 * wid + 16 * cb + 4 * lhi;
            const ushort4 vr = *reinterpret_cast<const ushort4*>(IN + ib + cq);
            const ushort4 vi = *reinterpret_cast<const ushort4*>(IN + ib + 128 + cq);
            const ushort4 vn = *reinterpret_cast<const ushort4*>(IN + ib + 256 + cq);
            const ushort4 vh = *reinterpret_cast<const ushort4*>(hbf + ob + cq);
            const unsigned short ra[4] = {vr.x, vr.y, vr.z, vr.w};
            const unsigned short ia[4] = {vi.x, vi.y, vi.z, vi.w};
            const unsigned short na[4] = {vn.x, vn.y, vn.z, vn.w};
            const unsigned short ha[4] = {vh.x, vh.y, vh.z, vh.w};
            unsigned short oa[4];
            #pragma unroll
            for (int j = 0; j < 4; j++) {
                float g_r = acc[0][cb][rb][j] + bf_bits2f(ra[j]);
                float g_i = acc[1][cb][rb][j] + bf_bits2f(ia[j]);
                float rr = sigmoidf_(g_r);
                float gi = sigmoidf_(g_i);
                float nn = tanhf(bf_bits2f(na[j]) + rr * acc[2][cb][rb][j]);
                oa[j] = f2bf_bits((1.f - gi) * nn + gi * bf_bits2f(ha[j]));
            }
            ushort4 st; st.x = oa[0]; st.y = oa[1]; st.z = oa[2]; st.w = oa[3];
            *reinterpret_cast<ushort4*>(hbf + ob + cq) = st;
        }
    }
}

// ---------------- generic MFMA GEMM: C = act(X@W + bias) ----------------------
// X: f32 (converted in flight) or bf16, row-major [M x K]; W pre-packed k-major.
// Swapped-operand layout: per-lane 4 consecutive cols of one row.
template<int K, int NC, bool F32IN, bool RELU, bool BF16OUT>
__global__ __launch_bounds__(256, 2) void mfma_gemm(
    const void* __restrict__ Xv, const unsigned short* __restrict__ WBx,
    const float* __restrict__ bias, void* __restrict__ C, int M)
{
    constexpr int KS = K / 32;
    constexpr int BI = NC / 64;
    constexpr int NCW = NC / 4;
    constexpr int CB = NCW / 16;
    __shared__ unsigned short As[64 * 32];
    __shared__ unsigned short Bs[NC * 32];

    const int tid = threadIdx.x;
    const int wid = tid >> 6;
    const int lane = tid & 63;
    const int l15 = lane & 15;
    const int lhi = lane >> 4;
    const int row0 = blockIdx.x * 64;

    f32x4 acc[CB][4] = {};

    const int ar = tid >> 2;
    const int aq = tid & 3;
    const int agr = row0 + ar;

    for (int s = 0; s < KS; s++) {
        {
            short8x va = short8x(0);
            if (agr < M) {
                if (F32IN) {
                    const float* src = (const float*)Xv + (size_t)agr * K + s * 32 + aq * 8;
                    const float4 f0 = *reinterpret_cast<const float4*>(src);
                    const float4 f1 = *reinterpret_cast<const float4*>(src + 4);
                    va[0] = (short)f2bf_bits(f0.x); va[1] = (short)f2bf_bits(f0.y);
                    va[2] = (short)f2bf_bits(f0.z); va[3] = (short)f2bf_bits(f0.w);
                    va[4] = (short)f2bf_bits(f1.x); va[5] = (short)f2bf_bits(f1.y);
                    va[6] = (short)f2bf_bits(f1.z); va[7] = (short)f2bf_bits(f1.w);
                } else {
                    va = *reinterpret_cast<const short8x*>(
                        (const unsigned short*)Xv + (size_t)agr * K + s * 32 + aq * 8);
                }
            }
            *reinterpret_cast<short8x*>(&As[swz8(ar, aq)]) = va;
        }
        {
            const unsigned short* wbs = WBx + (size_t)s * NC * 32;
            #pragma unroll
            for (int i = 0; i < BI; i++) {
                int id = tid + i * 256;
                int c = id >> 2, q = id & 3;
                short8x vb = *reinterpret_cast<const short8x*>(wbs + id * 8);
                *reinterpret_cast<short8x*>(&Bs[swz8(c, q)]) = vb;
            }
        }
        __syncthreads();

        short8x a[4];
        #pragma unroll
        for (int rb = 0; rb < 4; rb++)
            a[rb] = *reinterpret_cast<const short8x*>(&As[swz8(16 * rb + l15, lhi)]);
        #pragma unroll
        for (int cb = 0; cb < CB; cb++) {
            int c0 = NCW * wid + 16 * cb + l15;
            short8x b = *reinterpret_cast<const short8x*>(&Bs[swz8(c0, lhi)]);
            #pragma unroll
            for (int rb = 0; rb < 4; rb++)
                acc[cb][rb] = __builtin_amdgcn_mfma_f32_16x16x32_bf16(b, a[rb], acc[cb][rb], 0, 0, 0);
        }
        __syncthreads();
    }

    #pragma unroll
    for (int rb = 0; rb < 4; rb++) {
        int row = row0 + 16 * rb + l15;
        if (row >= M) continue;
        #pragma unroll
        for (int cb = 0; cb < CB; cb++) {
            int cq = NCW * wid + 16 * cb + 4 * lhi;
            float4 bv = make_float4(0.f, 0.f, 0.f, 0.f);
            if (bias) bv = *reinterpret_cast<const float4*>(bias + cq);
            const float bva[4] = {bv.x, bv.y, bv.z, bv.w};
            float o[4];
            #pragma unroll
            for (int j = 0; j < 4; j++) {
                float v = acc[cb][rb][j] + bva[j];
                if (RELU) v = fmaxf(v, 0.f);
                o[j] = v;
            }
            if (BF16OUT) {
                ushort4 st;
                st.x = f2bf_bits(o[0]); st.y = f2bf_bits(o[1]);
                st.z = f2bf_bits(o[2]); st.w = f2bf_bits(o[3]);
                *reinterpret_cast<ushort4*>((unsigned short*)C + (size_t)row * NC + cq) = st;
            } else {
                float4 st; st.x = o[0]; st.y = o[1]; st.z = o[2]; st.w = o[3];
                *reinterpret_cast<float4*>((float*)C + (size_t)row * NC + cq) = st;
            }
        }
    }
}

// ---------------- LayerNorm (torch variant), bf16 in -> f32 z + bf16 z --------
__global__ __launch_bounds__(256) void layernorm_bf(
    const unsigned short* __restrict__ x, const float* __restrict__ gamma,
    const float* __restrict__ beta, float* __restrict__ zout,
    unsigned short* __restrict__ zbf, int N)
{
    int v = blockIdx.x * 4 + (threadIdx.x >> 6);
    int lane = threadIdx.x & 63;
    if (v >= N) return;
    const unsigned short* xr = x + (size_t)v * NHID;
    float x0 = bf_bits2f(xr[lane]), x1 = bf_bits2f(xr[lane + 64]);
    float s = x0 + x1;
    #pragma unroll
    for (int off = 32; off; off >>= 1) s += __shfl_xor(s, off, 64);
    float mean = s * (1.f / 128.f);
    float d0 = x0 - mean, d1 = x1 - mean;
    float vs = d0 * d0 + d1 * d1;
    #pragma unroll
    for (int off = 32; off; off >>= 1) vs += __shfl_xor(vs, off, 64);
    float std_ = sqrtf(vs / 127.f);
    float inv = 1.f / (std_ + 1e-6f);
    float z0 = gamma[lane] * d0 * inv + beta[lane];
    float z1 = gamma[lane + 64] * d1 * inv + beta[lane + 64];
    size_t o = (size_t)v * NHID;
    zout[o + lane] = z0;
    zout[o + lane + 64] = z1;
    zbf[o + lane] = f2bf_bits(z0);
    zbf[o + lane + 64] = f2bf_bits(z1);
}

// ---------------- pair decoder, UV interleaved [M][256] -----------------------
__global__ __launch_bounds__(256) void decoder_pairs(
    const unsigned short* __restrict__ UV,
    const int* __restrict__ xi, const int* __restrict__ yi,
    const float* __restrict__ bd1, const float* __restrict__ Wd2,
    const float* __restrict__ bd2, float* __restrict__ dout, int P)
{
    __shared__ float b1s[128], w2s[128];
    if (threadIdx.x < 128) {
        b1s[threadIdx.x] = bd1[threadIdx.x];
        w2s[threadIdx.x] = Wd2[threadIdx.x];
    }
    __syncthreads();
    int p = blockIdx.x * 256 + threadIdx.x;
    if (p >= P) return;
    const unsigned short* ur = UV + (size_t)xi[p] * 256;
    const unsigned short* vr = UV + (size_t)yi[p] * 256 + 128;
    float part = 0.f;
    #pragma unroll
    for (int j0 = 0; j0 < 128; j0 += 8) {
        const uint4 ua = *reinterpret_cast<const uint4*>(ur + j0);
        const uint4 va = *reinterpret_cast<const uint4*>(vr + j0);
        float uf[8], vf[8];
        uf[0] = bf_bits2f((unsigned short)ua.x); uf[1] = bf_bits2f((unsigned short)(ua.x >> 16));
        uf[2] = bf_bits2f((unsigned short)ua.y); uf[3] = bf_bits2f((unsigned short)(ua.y >> 16));
        uf[4] = bf_bits2f((unsigned short)ua.z); uf[5] = bf_bits2f((unsigned short)(ua.z >> 16));
        uf[6] = bf_bits2f((unsigned short)ua.w); uf[7] = bf_bits2f((unsigned short)(ua.w >> 16));
        vf[0] = bf_bits2f((unsigned short)va.x); vf[1] = bf_bits2f((unsigned short)(va.x >> 16));
        vf[2] = bf_bits2f((unsigned short)va.y); vf[3] = bf_bits2f((unsigned short)(va.y >> 16));
        vf[4] = bf_bits2f((unsigned short)va.z); vf[5] = bf_bits2f((unsigned short)(va.z >> 16));
        vf[6] = bf_bits2f((unsigned short)va.w); vf[7] = bf_bits2f((unsigned short)(va.w >> 16));
        #pragma unroll
        for (int q = 0; q < 8; q++) {
            float t = uf[q] + vf[q] + b1s[j0 + q];
            part += fmaxf(t, 0.f) * w2s[j0 + q];
        }
    }
    dout[p] = sigmoidf_(part + bd2[0]);
}

// ---------------- launcher ----------------------------------------------------
extern "C" void kernel_launch(void* const* d_in, const int* in_sizes, int n_in,
                              void* d_out, int out_size, void* d_ws, size_t ws_size,
                              hipStream_t stream) {
    const float* inputs = (const float*)d_in[0];
    const int* edge_row = (const int*)d_in[1];
    const int* edge_col = (const int*)d_in[2];
    const float* edge_w = (const float*)d_in[3];
    const int* x_idx = (const int*)d_in[4];
    const int* y_idx = (const int*)d_in[5];
    const float* Wr_in = (const float*)d_in[6];  const float* br_in = (const float*)d_in[7];
    const float* Wi_in = (const float*)d_in[8];  const float* bi_in = (const float*)d_in[9];
    const float* Wn_in = (const float*)d_in[10]; const float* bn_in = (const float*)d_in[11];
    const float* Hr_self = (const float*)d_in[12]; const float* Hr_nb = (const float*)d_in[13];
    const float* Hi_self = (const float*)d_in[14]; const float* Hi_nb = (const float*)d_in[15];
    const float* Hh_self = (const float*)d_in[16]; const float* Hh_nb = (const float*)d_in[17];
    const float* W1 = (const float*)d_in[18]; const float* b1 = (const float*)d_in[19];
    const float* W2 = (const float*)d_in[20]; const float* b2 = (const float*)d_in[21];
    const float* W3 = (const float*)d_in[22]; const float* b3 = (const float*)d_in[23];
    const float* gamma = (const float*)d_in[24]; const float* beta = (const float*)d_in[25];
    const float* Wd1 = (const float*)d_in[26]; const float* bd1 = (const float*)d_in[27];
    const float* Wd2 = (const float*)d_in[28]; const float* bd2 = (const float*)d_in[29];

    float* out_d = (float*)d_out;            // [P]
    float* out_z = ((float*)d_out) + NPAIR;  // [N*128]

    // ---- workspace layout (~129 MB) ----
    char* base = (char*)d_ws;
    size_t off = 0;
    auto take = [&](size_t bytes) { void* p = base + off; off = (off + bytes + 255) & ~(size_t)255; return p; };
    int*            row_ptr = (int*)           take((size_t)(N_NODES + 1) * 4);
    unsigned short* WBg     = (unsigned short*)take((size_t)8 * 384 * 32 * 2);   // Hcat 256x384
    unsigned short* WBin    = (unsigned short*)take((size_t)8 * 384 * 32 * 2);   // Win 256x384
    unsigned short* WB1     = (unsigned short*)take((size_t)4 * 128 * 32 * 2);
    unsigned short* WB2     = (unsigned short*)take((size_t)4 * 128 * 32 * 2);
    unsigned short* WB3     = (unsigned short*)take((size_t)4 * 128 * 32 * 2);
    unsigned short* WBd     = (unsigned short*)take((size_t)4 * 256 * 32 * 2);
    float*          bin     = (float*)         take(384 * 4);
    unsigned short* IN      = (unsigned short*)take((size_t)N_NODES * 384 * 2);  // 76.8 MB; later x2 / UV
    unsigned short* hbf     = (unsigned short*)take((size_t)N_NODES * NHID * 2); // later x3 / zbf
    unsigned short* hsbf    = (unsigned short*)take((size_t)N_NODES * NHID * 2); // later x1 / x3
    if (off > ws_size) return;   // diagnostic marker: d stays 0 -> absmax == 0.586

    // 1. CSR row_ptr
    build_row_ptr<<<(N_NODES + 256) / 256, 256, 0, stream>>>(edge_row, NEDGE, N_NODES, row_ptr);
    // 2. pack all weights (bf16 k-major)
    pack_kmajor<<<64, 256, 0, stream>>>(Hr_self, 128, 128, WBg, 384, 0, 0);
    pack_kmajor<<<64, 256, 0, stream>>>(Hi_self, 128, 128, WBg, 384, 128, 0);
    pack_kmajor<<<64, 256, 0, stream>>>(Hh_self, 128, 128, WBg, 384, 256, 0);
    pack_kmajor<<<64, 256, 0, stream>>>(Hr_nb,   128, 128, WBg, 384, 0, 128);
    pack_kmajor<<<64, 256, 0, stream>>>(Hi_nb,   128, 128, WBg, 384, 128, 128);
    pack_kmajor<<<64, 256, 0, stream>>>(Hh_nb,   128, 128, WBg, 384, 256, 128);
    pack_kmajor<<<128, 256, 0, stream>>>(Wr_in, 256, 128, WBin, 384, 0, 0);
    pack_kmajor<<<128, 256, 0, stream>>>(Wi_in, 256, 128, WBin, 384, 128, 0);
    pack_kmajor<<<128, 256, 0, stream>>>(Wn_in, 256, 128, WBin, 384, 256, 0);
    pack_kmajor<<<64, 256, 0, stream>>>(W1, 128, 128, WB1, 128, 0, 0);
    pack_kmajor<<<64, 256, 0, stream>>>(W2, 128, 128, WB2, 128, 0, 0);
    pack_kmajor<<<64, 256, 0, stream>>>(W3, 128, 128, WB3, 128, 0, 0);
    pack_kmajor<<<64, 256, 0, stream>>>(Wd1,             128, 128, WBd, 256, 0, 0);
    pack_kmajor<<<64, 256, 0, stream>>>(Wd1 + 128 * 128, 128, 128, WBd, 256, 128, 0);
    pack_bin<<<2, 256, 0, stream>>>(br_in, bi_in, bn_in, bin);
    // 3. h = 0 (bf16 master)
    {
        long long n = (long long)N_NODES * NHID;
        zero_u16<<<(unsigned)((n + 255) / 256), 256, 0, stream>>>(hbf, n);
    }
    int grid64 = (N_NODES + 63) / 64;
    // 4. IN = inputs @ [Wr|Wi|Wn] + [br|bi|bn]  (one-time, bf16 [N][384])
    mfma_gemm<256, 384, true, false, true><<<grid64, 256, 0, stream>>>(inputs, WBin, bin, IN, N_NODES);
    // 5. recurrent steps
    for (int s = 0; s < NSTEPS; s++) {
        spmm_bf16_ilp<<<(N_NODES + 3) / 4, 256, 0, stream>>>(row_ptr, edge_col, edge_w, hbf, hsbf, N_NODES);
        gate_step_mfma<<<grid64, 256, 0, stream>>>(hsbf, hbf, IN, WBg, N_NODES);
    }
    // 6. MLP (bf16 chain): hbf -> x1(hsbf) -> x2(IN region) -> x3(hbf region)
    unsigned short* x1 = hsbf;
    unsigned short* x2 = IN;
    unsigned short* x3 = hbf;
    mfma_gemm<128, 128, false, true, true><<<grid64, 256, 0, stream>>>(hbf, WB1, b1, x1, N_NODES);
    mfma_gemm<128, 128, false, true, true><<<grid64, 256, 0, stream>>>(x1, WB2, b2, x2, N_NODES);
    mfma_gemm<128, 128, false, true, true><<<grid64, 256, 0, stream>>>(x2, WB3, b3, x3, N_NODES);
    // 7. LayerNorm: x3 -> f32 z (d_out) + bf16 z (hsbf region)
    unsigned short* zbf = hsbf;
    layernorm_bf<<<(N_NODES + 3) / 4, 256, 0, stream>>>(x3, gamma, beta, out_z, zbf, N_NODES);
    // 8. UV = z @ [Wd1_top | Wd1_bot]  (bf16 [N][256] into IN region)
    unsigned short* UV = IN;
    mfma_gemm<128, 256, false, false, true><<<grid64, 256, 0, stream>>>(zbf, WBd, nullptr, UV, N_NODES);
    // 9. pair decoder -> d (f32)
    decoder_pairs<<<(NPAIR + 255) / 256, 256, 0, stream>>>(
        UV, x_idx, y_idx, bd1, Wd2, bd2, out_d, NPAIR);
}

// Round 9
// 1085.202 us; speedup vs baseline: 6.3078x; 1.0421x over previous
//
#include <hip/hip_runtime.h>
#include <hip/hip_bf16.h>

#define N_NODES 100000
#define NFEAT 256
#define NHID 128
#define NEDGE 3200000
#define NPAIR 200000
#define NSTEPS 5

typedef __attribute__((ext_vector_type(8))) short short8x;   // 8 bf16 (4 VGPR)
typedef __attribute__((ext_vector_type(4))) float f32x4;

__device__ __forceinline__ float sigmoidf_(float x) {
    return 1.f / (1.f + __expf(-x));
}
__device__ __forceinline__ unsigned short f2bf_bits(float f) {
    union { float f; unsigned int u; } c; c.f = f;
    unsigned int r = (c.u + 0x7FFFu + ((c.u >> 16) & 1u)) >> 16;
    return (unsigned short)r;
}
__device__ __forceinline__ float bf_bits2f(unsigned short b) {
    union { float f; unsigned int u; } c; c.u = ((unsigned int)b) << 16;
    return c.f;
}
// conflict-free LDS chunk offset (ushorts): row of 32 bf16, chunk q (8 bf16)
__device__ __forceinline__ int swz8(int row, int q) {
    return row * 32 + ((q + (row >> 1)) & 3) * 8;
}

// ---------------- utility ------------------------------------------------------
__global__ void zero_u16(unsigned short* __restrict__ p, long long n) {
    long long i = (long long)blockIdx.x * blockDim.x + threadIdx.x;
    if (i < n) p[i] = 0;
}

__global__ void build_row_ptr(const int* __restrict__ rows, int E, int N, int* __restrict__ row_ptr) {
    int i = blockIdx.x * blockDim.x + threadIdx.x;
    if (i > N) return;
    int lo = 0, hi = E;
    while (lo < hi) {
        int mid = (lo + hi) >> 1;
        if (rows[mid] < i) lo = mid + 1; else hi = mid;
    }
    row_ptr[i] = lo;
}

// pack f32 [K x NCsrc] into bf16 K-step-major [ (k+koff)/32 ][ coff+j ][ (k+koff)%32 ]
__global__ void pack_kmajor(const float* __restrict__ W, int K, int NCsrc,
                            unsigned short* __restrict__ out, int NCtot, int coff, int koff) {
    int idx = blockIdx.x * blockDim.x + threadIdx.x;
    if (idx >= K * NCsrc) return;
    int k = idx / NCsrc, j = idx - k * NCsrc;
    int kg = k + koff;
    out[(size_t)(kg >> 5) * NCtot * 32 + (size_t)(coff + j) * 32 + (kg & 31)] = f2bf_bits(W[idx]);
}

__global__ void pack_bin(const float* __restrict__ br, const float* __restrict__ bi,
                         const float* __restrict__ bn, float* __restrict__ bin) {
    int i = blockIdx.x * blockDim.x + threadIdx.x;
    if (i >= 384) return;
    bin[i] = (i < 128) ? br[i] : (i < 256) ? bi[i - 128] : bn[i - 256];
}

// ---------------- SpMM (bf16), 4 edge streams x 4 unroll ----------------------
#define SPMM_ACC(hv, we) { \
    acc[0] += (we) * bf_bits2f((unsigned short)(hv).x); \
    acc[1] += (we) * bf_bits2f((unsigned short)((hv).x >> 16)); \
    acc[2] += (we) * bf_bits2f((unsigned short)(hv).y); \
    acc[3] += (we) * bf_bits2f((unsigned short)((hv).y >> 16)); \
    acc[4] += (we) * bf_bits2f((unsigned short)(hv).z); \
    acc[5] += (we) * bf_bits2f((unsigned short)((hv).z >> 16)); \
    acc[6] += (we) * bf_bits2f((unsigned short)(hv).w); \
    acc[7] += (we) * bf_bits2f((unsigned short)((hv).w >> 16)); }

__global__ __launch_bounds__(256) void spmm_bf16_ilp(
    const int* __restrict__ row_ptr, const int* __restrict__ col,
    const float* __restrict__ w, const unsigned short* __restrict__ hbf,
    unsigned short* __restrict__ hsbf, int N)
{
    int v = blockIdx.x * 4 + (threadIdx.x >> 6);
    int lane = threadIdx.x & 63;
    int g = lane >> 4;
    int l16 = lane & 15;
    if (v >= N) return;
    int e0 = row_ptr[v], e1 = row_ptr[v + 1];
    float acc[8] = {};
    int e = e0 + g;
    for (; e + 12 < e1; e += 16) {
        int c1 = col[e], c2 = col[e + 4], c3 = col[e + 8], c4 = col[e + 12];
        float w1 = w[e], w2 = w[e + 4], w3 = w[e + 8], w4 = w[e + 12];
        const uint4 h1 = *reinterpret_cast<const uint4*>(hbf + (size_t)c1 * NHID + l16 * 8);
        const uint4 h2 = *reinterpret_cast<const uint4*>(hbf + (size_t)c2 * NHID + l16 * 8);
        const uint4 h3 = *reinterpret_cast<const uint4*>(hbf + (size_t)c3 * NHID + l16 * 8);
        const uint4 h4 = *reinterpret_cast<const uint4*>(hbf + (size_t)c4 * NHID + l16 * 8);
        SPMM_ACC(h1, w1) SPMM_ACC(h2, w2) SPMM_ACC(h3, w3) SPMM_ACC(h4, w4)
    }
    for (; e < e1; e += 4) {
        int cc = col[e];
        float we = w[e];
        const uint4 hv = *reinterpret_cast<const uint4*>(hbf + (size_t)cc * NHID + l16 * 8);
        SPMM_ACC(hv, we)
    }
    #pragma unroll
    for (int q = 0; q < 8; q++) {
        acc[q] += __shfl_xor(acc[q], 16, 64);
        acc[q] += __shfl_xor(acc[q], 32, 64);
    }
    if (g == 0) {
        uint4 o;
        o.x = (unsigned int)f2bf_bits(acc[0]) | ((unsigned int)f2bf_bits(acc[1]) << 16);
        o.y = (unsigned int)f2bf_bits(acc[2]) | ((unsigned int)f2bf_bits(acc[3]) << 16);
        o.z = (unsigned int)f2bf_bits(acc[4]) | ((unsigned int)f2bf_bits(acc[5]) << 16);
        o.w = (unsigned int)f2bf_bits(acc[6]) | ((unsigned int)f2bf_bits(acc[7]) << 16);
        *reinterpret_cast<uint4*>(hsbf + (size_t)v * NHID + l16 * 8) = o;
    }
}

// ---------------- per-step gate GEMM (K=256) + GRU, h bf16 in place -----------
__global__ __launch_bounds__(256, 2) void gate_step_mfma(
    const unsigned short* __restrict__ hsbf, unsigned short* __restrict__ hbf,
    const unsigned short* __restrict__ IN, const unsigned short* __restrict__ WBg, int M)
{
    __shared__ unsigned short As[64 * 32];
    __shared__ unsigned short Bs[384 * 32];

    const int tid = threadIdx.x;
    const int wid = tid >> 6;
    const int lane = tid & 63;
    const int row0 = blockIdx.x * 64;
    const int l15 = lane & 15;
    const int lhi = lane >> 4;

    f32x4 acc[3][2][4] = {};

    const int ar = tid >> 2;
    const int aq = tid & 3;
    const int agr = row0 + ar;

    for (int s = 0; s < 8; s++) {
        {
            short8x va = short8x(0);
            if (agr < M) {
                const unsigned short* src = (s < 4)
                    ? (hbf  + (size_t)agr * 128 + s * 32)
                    : (hsbf + (size_t)agr * 128 + (s - 4) * 32);
                va = *reinterpret_cast<const short8x*>(src + aq * 8);
            }
            *reinterpret_cast<short8x*>(&As[swz8(ar, aq)]) = va;
        }
        {
            const unsigned short* wbs = WBg + (size_t)s * 384 * 32;
            #pragma unroll
            for (int i = 0; i < 6; i++) {
                int id = tid + i * 256;
                int c = id >> 2, q = id & 3;
                short8x vb = *reinterpret_cast<const short8x*>(wbs + id * 8);
                *reinterpret_cast<short8x*>(&Bs[swz8(c, q)]) = vb;
            }
        }
        __syncthreads();

        short8x a[4];
        #pragma unroll
        for (int rb = 0; rb < 4; rb++)
            a[rb] = *reinterpret_cast<const short8x*>(&As[swz8(16 * rb + l15, lhi)]);
        #pragma unroll
        for (int p = 0; p < 3; p++) {
            #pragma unroll
            for (int cb = 0; cb < 2; cb++) {
                int c0 = 128 * p + 32 * wid + 16 * cb + l15;
                short8x b = *reinterpret_cast<const short8x*>(&Bs[swz8(c0, lhi)]);
                #pragma unroll
                for (int rb = 0; rb < 4; rb++)
                    acc[p][cb][rb] = __builtin_amdgcn_mfma_f32_16x16x32_bf16(b, a[rb], acc[p][cb][rb], 0, 0, 0);
            }
        }
        __syncthreads();
    }

    // GRU epilogue: per lane, row = row0+16rb+l15, 4 consecutive cols
    #pragma unroll
    for (int rb = 0; rb < 4; rb++) {
        int row = row0 + 16 * rb + l15;
        if (row >= M) continue;
        size_t ib = (size_t)row * 384;
        size_t ob = (size_t)row * 128;
        #pragma unroll
        for (int cb = 0; cb < 2; cb++) {
            int cq = 32 * wid + 16 * cb + 4 * lhi;
            const ushort4 vr = *reinterpret_cast<const ushort4*>(IN + ib + cq);
            const ushort4 vi = *reinterpret_cast<const ushort4*>(IN + ib + 128 + cq);
            const ushort4 vn = *reinterpret_cast<const ushort4*>(IN + ib + 256 + cq);
            const ushort4 vh = *reinterpret_cast<const ushort4*>(hbf + ob + cq);
            const unsigned short ra[4] = {vr.x, vr.y, vr.z, vr.w};
            const unsigned short ia[4] = {vi.x, vi.y, vi.z, vi.w};
            const unsigned short na[4] = {vn.x, vn.y, vn.z, vn.w};
            const unsigned short ha[4] = {vh.x, vh.y, vh.z, vh.w};
            unsigned short oa[4];
            #pragma unroll
            for (int j = 0; j < 4; j++) {
                float g_r = acc[0][cb][rb][j] + bf_bits2f(ra[j]);
                float g_i = acc[1][cb][rb][j] + bf_bits2f(ia[j]);
                float rr = sigmoidf_(g_r);
                float gi = sigmoidf_(g_i);
                float nn = tanhf(bf_bits2f(na[j]) + rr * acc[2][cb][rb][j]);
                oa[j] = f2bf_bits((1.f - gi) * nn + gi * bf_bits2f(ha[j]));
            }
            ushort4 st; st.x = oa[0]; st.y = oa[1]; st.z = oa[2]; st.w = oa[3];
            *reinterpret_cast<ushort4*>(hbf + ob + cq) = st;
        }
    }
}

// ---------------- generic MFMA GEMM (used for IN-proj) ------------------------
template<int K, int NC, bool F32IN, bool RELU, bool BF16OUT>
__global__ __launch_bounds__(256, 2) void mfma_gemm(
    const void* __restrict__ Xv, const unsigned short* __restrict__ WBx,
    const float* __restrict__ bias, void* __restrict__ C, int M)
{
    constexpr int KS = K / 32;
    constexpr int BI = NC / 64;
    constexpr int NCW = NC / 4;
    constexpr int CB = NCW / 16;
    __shared__ unsigned short As[64 * 32];
    __shared__ unsigned short Bs[NC * 32];

    const int tid = threadIdx.x;
    const int wid = tid >> 6;
    const int lane = tid & 63;
    const int l15 = lane & 15;
    const int lhi = lane >> 4;
    const int row0 = blockIdx.x * 64;

    f32x4 acc[CB][4] = {};

    const int ar = tid >> 2;
    const int aq = tid & 3;
    const int agr = row0 + ar;

    for (int s = 0; s < KS; s++) {
        {
            short8x va = short8x(0);
            if (agr < M) {
                if (F32IN) {
                    const float* src = (const float*)Xv + (size_t)agr * K + s * 32 + aq * 8;
                    const float4 f0 = *reinterpret_cast<const float4*>(src);
                    const float4 f1 = *reinterpret_cast<const float4*>(src + 4);
                    va[0] = (short)f2bf_bits(f0.x); va[1] = (short)f2bf_bits(f0.y);
                    va[2] = (short)f2bf_bits(f0.z); va[3] = (short)f2bf_bits(f0.w);
                    va[4] = (short)f2bf_bits(f1.x); va[5] = (short)f2bf_bits(f1.y);
                    va[6] = (short)f2bf_bits(f1.z); va[7] = (short)f2bf_bits(f1.w);
                } else {
                    va = *reinterpret_cast<const short8x*>(
                        (const unsigned short*)Xv + (size_t)agr * K + s * 32 + aq * 8);
                }
            }
            *reinterpret_cast<short8x*>(&As[swz8(ar, aq)]) = va;
        }
        {
            const unsigned short* wbs = WBx + (size_t)s * NC * 32;
            #pragma unroll
            for (int i = 0; i < BI; i++) {
                int id = tid + i * 256;
                int c = id >> 2, q = id & 3;
                short8x vb = *reinterpret_cast<const short8x*>(wbs + id * 8);
                *reinterpret_cast<short8x*>(&Bs[swz8(c, q)]) = vb;
            }
        }
        __syncthreads();

        short8x a[4];
        #pragma unroll
        for (int rb = 0; rb < 4; rb++)
            a[rb] = *reinterpret_cast<const short8x*>(&As[swz8(16 * rb + l15, lhi)]);
        #pragma unroll
        for (int cb = 0; cb < CB; cb++) {
            int c0 = NCW * wid + 16 * cb + l15;
            short8x b = *reinterpret_cast<const short8x*>(&Bs[swz8(c0, lhi)]);
            #pragma unroll
            for (int rb = 0; rb < 4; rb++)
                acc[cb][rb] = __builtin_amdgcn_mfma_f32_16x16x32_bf16(b, a[rb], acc[cb][rb], 0, 0, 0);
        }
        __syncthreads();
    }

    #pragma unroll
    for (int rb = 0; rb < 4; rb++) {
        int row = row0 + 16 * rb + l15;
        if (row >= M) continue;
        #pragma unroll
        for (int cb = 0; cb < CB; cb++) {
            int cq = NCW * wid + 16 * cb + 4 * lhi;
            float4 bv = make_float4(0.f, 0.f, 0.f, 0.f);
            if (bias) bv = *reinterpret_cast<const float4*>(bias + cq);
            const float bva[4] = {bv.x, bv.y, bv.z, bv.w};
            float o[4];
            #pragma unroll
            for (int j = 0; j < 4; j++) {
                float v = acc[cb][rb][j] + bva[j];
                if (RELU) v = fmaxf(v, 0.f);
                o[j] = v;
            }
            if (BF16OUT) {
                ushort4 st;
                st.x = f2bf_bits(o[0]); st.y = f2bf_bits(o[1]);
                st.z = f2bf_bits(o[2]); st.w = f2bf_bits(o[3]);
                *reinterpret_cast<ushort4*>((unsigned short*)C + (size_t)row * NC + cq) = st;
            } else {
                float4 st; st.x = o[0]; st.y = o[1]; st.z = o[2]; st.w = o[3];
                *reinterpret_cast<float4*>((float*)C + (size_t)row * NC + cq) = st;
            }
        }
    }
}

// ---------------- fused tail: MLP x3 + LayerNorm + UV GEMM --------------------
// Activation tile for 64 rows lives in LDS (xT, stride 136) across all stages.
#define XT_STRIDE 136
__global__ __launch_bounds__(256, 2) void mlp_tail(
    const unsigned short* __restrict__ hbf,
    const unsigned short* __restrict__ WB1, const unsigned short* __restrict__ WB2,
    const unsigned short* __restrict__ WB3, const unsigned short* __restrict__ WBd,
    const float* __restrict__ b1, const float* __restrict__ b2, const float* __restrict__ b3,
    const float* __restrict__ gamma, const float* __restrict__ beta,
    float* __restrict__ out_z, unsigned short* __restrict__ UV, int M)
{
    __shared__ unsigned short As[64 * 32];          // 4 KB
    __shared__ unsigned short Bs[256 * 32];         // 16 KB
    __shared__ unsigned short xT[64 * XT_STRIDE];   // 17.4 KB

    const int tid = threadIdx.x;
    const int wid = tid >> 6;
    const int lane = tid & 63;
    const int l15 = lane & 15;
    const int lhi = lane >> 4;
    const int row0 = blockIdx.x * 64;
    const int ar = tid >> 2;
    const int aq = tid & 3;

    // ---- load h tile into xT (zero OOB rows) ----
    #pragma unroll
    for (int i = 0; i < 4; i++) {
        int id = tid + i * 256;            // 0..1023, 8 ushorts each
        int r = id >> 4, ch = id & 15;
        short8x v = short8x(0);
        if (row0 + r < M)
            v = *reinterpret_cast<const short8x*>(hbf + (size_t)(row0 + r) * 128 + ch * 8);
        *reinterpret_cast<short8x*>(&xT[r * XT_STRIDE + ch * 8]) = v;
    }
    __syncthreads();

    // ---- 3 MLP layers, activation stays in xT ----
    const unsigned short* WLs[3] = {WB1, WB2, WB3};
    const float* bLs[3] = {b1, b2, b3};
    for (int L = 0; L < 3; L++) {
        f32x4 acc[2][4] = {};
        for (int s = 0; s < 4; s++) {
            {
                short8x va = *reinterpret_cast<const short8x*>(&xT[ar * XT_STRIDE + s * 32 + aq * 8]);
                *reinterpret_cast<short8x*>(&As[swz8(ar, aq)]) = va;
            }
            {
                const unsigned short* wbs = WLs[L] + (size_t)s * 128 * 32;
                #pragma unroll
                for (int i = 0; i < 2; i++) {
                    int id = tid + i * 256;
                    int c = id >> 2, q = id & 3;
                    short8x vb = *reinterpret_cast<const short8x*>(wbs + id * 8);
                    *reinterpret_cast<short8x*>(&Bs[swz8(c, q)]) = vb;
                }
            }
            __syncthreads();
            short8x a[4];
            #pragma unroll
            for (int rb = 0; rb < 4; rb++)
                a[rb] = *reinterpret_cast<const short8x*>(&As[swz8(16 * rb + l15, lhi)]);
            #pragma unroll
            for (int cb = 0; cb < 2; cb++) {
                int c0 = 32 * wid + 16 * cb + l15;
                short8x b = *reinterpret_cast<const short8x*>(&Bs[swz8(c0, lhi)]);
                #pragma unroll
                for (int rb = 0; rb < 4; rb++)
                    acc[cb][rb] = __builtin_amdgcn_mfma_f32_16x16x32_bf16(b, a[rb], acc[cb][rb], 0, 0, 0);
            }
            __syncthreads();
        }
        // writeback: relu(acc + bias) -> xT
        #pragma unroll
        for (int rb = 0; rb < 4; rb++) {
            int r = 16 * rb + l15;
            #pragma unroll
            for (int cb = 0; cb < 2; cb++) {
                int cq = 32 * wid + 16 * cb + 4 * lhi;
                const float4 bv = *reinterpret_cast<const float4*>(bLs[L] + cq);
                const float bva[4] = {bv.x, bv.y, bv.z, bv.w};
                ushort4 st;
                unsigned short* o = (unsigned short*)&st;
                #pragma unroll
                for (int j = 0; j < 4; j++)
                    o[j] = f2bf_bits(fmaxf(acc[cb][rb][j] + bva[j], 0.f));
                *reinterpret_cast<ushort4*>(&xT[r * XT_STRIDE + cq]) = st;
            }
        }
        __syncthreads();
    }

    // ---- LayerNorm (torch: ddof=1, eps on std); z f32 -> out_z, bf16 -> xT ----
    {
        int r = tid >> 2;              // row 0..63
        int grp = tid & 3;             // 32 cols each
        int c0 = grp * 32;
        float xv[32];
        #pragma unroll
        for (int k = 0; k < 4; k++) {
            short8x v = *reinterpret_cast<const short8x*>(&xT[r * XT_STRIDE + c0 + k * 8]);
            #pragma unroll
            for (int j = 0; j < 8; j++) xv[k * 8 + j] = bf_bits2f((unsigned short)v[j]);
        }
        float s = 0.f;
        #pragma unroll
        for (int q = 0; q < 32; q++) s += xv[q];
        s += __shfl_xor(s, 1, 64);
        s += __shfl_xor(s, 2, 64);
        float mean = s * (1.f / 128.f);
        float vs = 0.f;
        #pragma unroll
        for (int q = 0; q < 32; q++) { float d = xv[q] - mean; vs += d * d; }
        vs += __shfl_xor(vs, 1, 64);
        vs += __shfl_xor(vs, 2, 64);
        float inv = 1.f / (sqrtf(vs / 127.f) + 1e-6f);
        int grow = row0 + r;
        #pragma unroll
        for (int k = 0; k < 4; k++) {
            const float4 gm = *reinterpret_cast<const float4*>(gamma + c0 + k * 8);
            const float4 gm2 = *reinterpret_cast<const float4*>(gamma + c0 + k * 8 + 4);
            const float4 bt = *reinterpret_cast<const float4*>(beta + c0 + k * 8);
            const float4 bt2 = *reinterpret_cast<const float4*>(beta + c0 + k * 8 + 4);
            const float gms[8] = {gm.x, gm.y, gm.z, gm.w, gm2.x, gm2.y, gm2.z, gm2.w};
            const float bts[8] = {bt.x, bt.y, bt.z, bt.w, bt2.x, bt2.y, bt2.z, bt2.w};
            float z[8];
            short8x zb;
            #pragma unroll
            for (int j = 0; j < 8; j++) {
                z[j] = gms[j] * (xv[k * 8 + j] - mean) * inv + bts[j];
                zb[j] = (short)f2bf_bits(z[j]);
            }
            *reinterpret_cast<short8x*>(&xT[r * XT_STRIDE + c0 + k * 8]) = zb;
            if (grow < M) {
                float4 z0 = make_float4(z[0], z[1], z[2], z[3]);
                float4 z1 = make_float4(z[4], z[5], z[6], z[7]);
                *reinterpret_cast<float4*>(out_z + (size_t)grow * 128 + c0 + k * 8) = z0;
                *reinterpret_cast<float4*>(out_z + (size_t)grow * 128 + c0 + k * 8 + 4) = z1;
            }
        }
    }
    __syncthreads();

    // ---- UV = z @ WBd (K=128, NC=256), bf16 out ----
    {
        f32x4 acc[4][4] = {};
        for (int s = 0; s < 4; s++) {
            {
                short8x va = *reinterpret_cast<const short8x*>(&xT[ar * XT_STRIDE + s * 32 + aq * 8]);
                *reinterpret_cast<short8x*>(&As[swz8(ar, aq)]) = va;
            }
            {
                const unsigned short* wbs = WBd + (size_t)s * 256 * 32;
                #pragma unroll
                for (int i = 0; i < 4; i++) {
                    int id = tid + i * 256;
                    int c = id >> 2, q = id & 3;
                    short8x vb = *reinterpret_cast<const short8x*>(wbs + id * 8);
                    *reinterpret_cast<short8x*>(&Bs[swz8(c, q)]) = vb;
                }
            }
            __syncthreads();
            short8x a[4];
            #pragma unroll
            for (int rb = 0; rb < 4; rb++)
                a[rb] = *reinterpret_cast<const short8x*>(&As[swz8(16 * rb + l15, lhi)]);
            #pragma unroll
            for (int cb = 0; cb < 4; cb++) {
                int c0 = 64 * wid + 16 * cb + l15;
                short8x b = *reinterpret_cast<const short8x*>(&Bs[swz8(c0, lhi)]);
                #pragma unroll
                for (int rb = 0; rb < 4; rb++)
                    acc[cb][rb] = __builtin_amdgcn_mfma_f32_16x16x32_bf16(b, a[rb], acc[cb][rb], 0, 0, 0);
            }
            __syncthreads();
        }
        #pragma unroll
        for (int rb = 0; rb < 4; rb++) {
            int row = row0 + 16 * rb + l15;
            if (row >= M) continue;
            #pragma unroll
            for (int cb = 0; cb < 4; cb++) {
                int cq = 64 * wid + 16 * cb + 4 * lhi;
                ushort4 st;
                st.x = f2bf_bits(acc[cb][rb][0]); st.y = f2bf_bits(acc[cb][rb][1]);
                st.z = f2bf_bits(acc[cb][rb][2]); st.w = f2bf_bits(acc[cb][rb][3]);
                *reinterpret_cast<ushort4*>(UV + (size_t)row * 256 + cq) = st;
            }
        }
    }
}

// ---------------- pair decoder, UV interleaved [M][256] -----------------------
__global__ __launch_bounds__(256) void decoder_pairs(
    const unsigned short* __restrict__ UV,
    const int* __restrict__ xi, const int* __restrict__ yi,
    const float* __restrict__ bd1, const float* __restrict__ Wd2,
    const float* __restrict__ bd2, float* __restrict__ dout, int P)
{
    __shared__ float b1s[128], w2s[128];
    if (threadIdx.x < 128) {
        b1s[threadIdx.x] = bd1[threadIdx.x];
        w2s[threadIdx.x] = Wd2[threadIdx.x];
    }
    __syncthreads();
    int p = blockIdx.x * 256 + threadIdx.x;
    if (p >= P) return;
    const unsigned short* ur = UV + (size_t)xi[p] * 256;
    const unsigned short* vr = UV + (size_t)yi[p] * 256 + 128;
    float part = 0.f;
    #pragma unroll
    for (int j0 = 0; j0 < 128; j0 += 8) {
        const uint4 ua = *reinterpret_cast<const uint4*>(ur + j0);
        const uint4 va = *reinterpret_cast<const uint4*>(vr + j0);
        float uf[8], vf[8];
        uf[0] = bf_bits2f((unsigned short)ua.x); uf[1] = bf_bits2f((unsigned short)(ua.x >> 16));
        uf[2] = bf_bits2f((unsigned short)ua.y); uf[3] = bf_bits2f((unsigned short)(ua.y >> 16));
        uf[4] = bf_bits2f((unsigned short)ua.z); uf[5] = bf_bits2f((unsigned short)(ua.z >> 16));
        uf[6] = bf_bits2f((unsigned short)ua.w); uf[7] = bf_bits2f((unsigned short)(ua.w >> 16));
        vf[0] = bf_bits2f((unsigned short)va.x); vf[1] = bf_bits2f((unsigned short)(va.x >> 16));
        vf[2] = bf_bits2f((unsigned short)va.y); vf[3] = bf_bits2f((unsigned short)(va.y >> 16));
        vf[4] = bf_bits2f((unsigned short)va.z); vf[5] = bf_bits2f((unsigned short)(va.z >> 16));
        vf[6] = bf_bits2f((unsigned short)va.w); vf[7] = bf_bits2f((unsigned short)(va.w >> 16));
        #pragma unroll
        for (int q = 0; q < 8; q++) {
            float t = uf[q] + vf[q] + b1s[j0 + q];
            part += fmaxf(t, 0.f) * w2s[j0 + q];
        }
    }
    dout[p] = sigmoidf_(part + bd2[0]);
}

// ---------------- launcher ----------------------------------------------------
extern "C" void kernel_launch(void* const* d_in, const int* in_sizes, int n_in,
                              void* d_out, int out_size, void* d_ws, size_t ws_size,
                              hipStream_t stream) {
    const float* inputs = (const float*)d_in[0];
    const int* edge_row = (const int*)d_in[1];
    const int* edge_col = (const int*)d_in[2];
    const float* edge_w = (const float*)d_in[3];
    const int* x_idx = (const int*)d_in[4];
    const int* y_idx = (const int*)d_in[5];
    const float* Wr_in = (const float*)d_in[6];  const float* br_in = (const float*)d_in[7];
    const float* Wi_in = (const float*)d_in[8];  const float* bi_in = (const float*)d_in[9];
    const float* Wn_in = (const float*)d_in[10]; const float* bn_in = (const float*)d_in[11];
    const float* Hr_self = (const float*)d_in[12]; const float* Hr_nb = (const float*)d_in[13];
    const float* Hi_self = (const float*)d_in[14]; const float* Hi_nb = (const float*)d_in[15];
    const float* Hh_self = (const float*)d_in[16]; const float* Hh_nb = (const float*)d_in[17];
    const float* W1 = (const float*)d_in[18]; const float* b1 = (const float*)d_in[19];
    const float* W2 = (const float*)d_in[20]; const float* b2 = (const float*)d_in[21];
    const float* W3 = (const float*)d_in[22]; const float* b3 = (const float*)d_in[23];
    const float* gamma = (const float*)d_in[24]; const float* beta = (const float*)d_in[25];
    const float* Wd1 = (const float*)d_in[26]; const float* bd1 = (const float*)d_in[27];
    const float* Wd2 = (const float*)d_in[28]; const float* bd2 = (const float*)d_in[29];

    float* out_d = (float*)d_out;            // [P]
    float* out_z = ((float*)d_out) + NPAIR;  // [N*128]

    // ---- workspace layout (~129 MB) ----
    char* base = (char*)d_ws;
    size_t off = 0;
    auto take = [&](size_t bytes) { void* p = base + off; off = (off + bytes + 255) & ~(size_t)255; return p; };
    int*            row_ptr = (int*)           take((size_t)(N_NODES + 1) * 4);
    unsigned short* WBg     = (unsigned short*)take((size_t)8 * 384 * 32 * 2);   // Hcat 256x384
    unsigned short* WBin    = (unsigned short*)take((size_t)8 * 384 * 32 * 2);   // Win 256x384
    unsigned short* WB1     = (unsigned short*)take((size_t)4 * 128 * 32 * 2);
    unsigned short* WB2     = (unsigned short*)take((size_t)4 * 128 * 32 * 2);
    unsigned short* WB3     = (unsigned short*)take((size_t)4 * 128 * 32 * 2);
    unsigned short* WBd     = (unsigned short*)take((size_t)4 * 256 * 32 * 2);
    float*          bin     = (float*)         take(384 * 4);
    unsigned short* IN      = (unsigned short*)take((size_t)N_NODES * 384 * 2);  // 76.8 MB; later UV
    unsigned short* hbf     = (unsigned short*)take((size_t)N_NODES * NHID * 2);
    unsigned short* hsbf    = (unsigned short*)take((size_t)N_NODES * NHID * 2);
    if (off > ws_size) return;   // diagnostic marker: d stays 0 -> absmax == 0.586

    // 1. CSR row_ptr
    build_row_ptr<<<(N_NODES + 256) / 256, 256, 0, stream>>>(edge_row, NEDGE, N_NODES, row_ptr);
    // 2. pack all weights (bf16 k-major)
    pack_kmajor<<<64, 256, 0, stream>>>(Hr_self, 128, 128, WBg, 384, 0, 0);
    pack_kmajor<<<64, 256, 0, stream>>>(Hi_self, 128, 128, WBg, 384, 128, 0);
    pack_kmajor<<<64, 256, 0, stream>>>(Hh_self, 128, 128, WBg, 384, 256, 0);
    pack_kmajor<<<64, 256, 0, stream>>>(Hr_nb,   128, 128, WBg, 384, 0, 128);
    pack_kmajor<<<64, 256, 0, stream>>>(Hi_nb,   128, 128, WBg, 384, 128, 128);
    pack_kmajor<<<64, 256, 0, stream>>>(Hh_nb,   128, 128, WBg, 384, 256, 128);
    pack_kmajor<<<128, 256, 0, stream>>>(Wr_in, 256, 128, WBin, 384, 0, 0);
    pack_kmajor<<<128, 256, 0, stream>>>(Wi_in, 256, 128, WBin, 384, 128, 0);
    pack_kmajor<<<128, 256, 0, stream>>>(Wn_in, 256, 128, WBin, 384, 256, 0);
    pack_kmajor<<<64, 256, 0, stream>>>(W1, 128, 128, WB1, 128, 0, 0);
    pack_kmajor<<<64, 256, 0, stream>>>(W2, 128, 128, WB2, 128, 0, 0);
    pack_kmajor<<<64, 256, 0, stream>>>(W3, 128, 128, WB3, 128, 0, 0);
    pack_kmajor<<<64, 256, 0, stream>>>(Wd1,             128, 128, WBd, 256, 0, 0);
    pack_kmajor<<<64, 256, 0, stream>>>(Wd1 + 128 * 128, 128, 128, WBd, 256, 128, 0);
    pack_bin<<<2, 256, 0, stream>>>(br_in, bi_in, bn_in, bin);
    // 3. h = 0 (bf16 master)
    {
        long long n = (long long)N_NODES * NHID;
        zero_u16<<<(unsigned)((n + 255) / 256), 256, 0, stream>>>(hbf, n);
    }
    int grid64 = (N_NODES + 63) / 64;
    // 4. IN = inputs @ [Wr|Wi|Wn] + [br|bi|bn]  (one-time, bf16 [N][384])
    mfma_gemm<256, 384, true, false, true><<<grid64, 256, 0, stream>>>(inputs, WBin, bin, IN, N_NODES);
    // 5. recurrent steps
    for (int s = 0; s < NSTEPS; s++) {
        spmm_bf16_ilp<<<(N_NODES + 3) / 4, 256, 0, stream>>>(row_ptr, edge_col, edge_w, hbf, hsbf, N_NODES);
        gate_step_mfma<<<grid64, 256, 0, stream>>>(hsbf, hbf, IN, WBg, N_NODES);
    }
    // 6. fused tail: MLP x3 + LayerNorm (z f32 -> d_out) + UV GEMM
    unsigned short* UV = IN;
    mlp_tail<<<grid64, 256, 0, stream>>>(hbf, WB1, WB2, WB3, WBd, b1, b2, b3,
                                         gamma, beta, out_z, UV, N_NODES);
    // 7. pair decoder -> d (f32)
    decoder_pairs<<<(NPAIR + 255) / 256, 256, 0, stream>>>(
        UV, x_idx, y_idx, bd1, Wd2, bd2, out_d, NPAIR);
}